// Round 3
// baseline (334.825 us; speedup 1.0000x reference)
//
#include <hip/hip_runtime.h>
#include <stdint.h>

typedef unsigned short u16;
typedef unsigned int u32;

#define B_ 16
#define V_ 16
#define M_ 32
#define L_ 24
#define D_ 128
#define G_ 384   // 3*D
#define N_ 256   // B*V
#define NM_ 8192 // B*V*M
#define OUT_ 193

using bf16x8 = __attribute__((ext_vector_type(8))) __bf16;
using floatx4 = __attribute__((ext_vector_type(4))) float;

__device__ __forceinline__ float bf2f(u16 u) {
  u32 x = ((u32)u) << 16;
  return __builtin_bit_cast(float, x);
}
__device__ __forceinline__ u16 f2bf(float f) {
  u32 u = __builtin_bit_cast(u32, f);
  u = (u + 0x7FFFu + ((u >> 16) & 1u)) >> 16;
  return (u16)u;
}
__device__ __forceinline__ float sigm_(float x) {
  return 1.0f / (1.0f + __expf(-x));
}
__device__ __forceinline__ float tanh_(float x) {
  float e = __expf(2.0f * x);
  return 1.0f - 2.0f / (e + 1.0f);
}
__device__ __forceinline__ floatx4 mfma16(bf16x8 a, bf16x8 b, floatx4 c) {
  return __builtin_amdgcn_mfma_f32_16x16x32_bf16(a, b, c, 0, 0, 0);
}

// ---------------- Kernel 0: convert f32 GRU weights -> hi/lo bf16 planes ----------------
// dst layout: wih plane = [mgru(5) | vgru(7)][384][128]; whh plane likewise.
__global__ __launch_bounds__(256) void k_conv_w(
    const float* __restrict__ mwih, const float* __restrict__ vwih,
    const float* __restrict__ mwhh, const float* __restrict__ vwhh,
    u16* __restrict__ wih_hi, u16* __restrict__ wih_lo,
    u16* __restrict__ whh_hi, u16* __restrict__ whh_lo) {
  const int S5 = 5 * G_ * D_, S12 = 12 * G_ * D_;
  int i = blockIdx.x * 256 + threadIdx.x;
  float v;
  u16 *dh, *dl;
  int o;
  if (i < S12) {
    o = i;
    v = (o < S5) ? mwih[o] : vwih[o - S5];
    dh = wih_hi; dl = wih_lo;
  } else {
    o = i - S12;
    v = (o < S5) ? mwhh[o] : vwhh[o - S5];
    dh = whh_hi; dl = whh_lo;
  }
  u16 h = f2bf(v);
  dh[o] = h;
  dl[o] = f2bf(v - bf2f(h));
}

// ---------------- Kernel 1: visit-event embeddings + info linears ----------------
__global__ __launch_bounds__(128) void k_visit_embed(
    const int* __restrict__ tc, const int* __restrict__ tp, const int* __restrict__ td,
    const float* __restrict__ ec, const float* __restrict__ ep, const float* __restrict__ ed,
    const float* __restrict__ wv, const float* __restrict__ av,
    const float* __restrict__ iw, const float* __restrict__ ib,
    u16* __restrict__ ce_hi, u16* __restrict__ ce_lo,
    u16* __restrict__ vx_hi, u16* __restrict__ vx_lo) {
  int n = blockIdx.x, d = threadIdx.x;
  float a0 = 0.f, a1 = 0.f, a2 = 0.f;
#pragma unroll 4
  for (int l = 0; l < L_; l++) {
    a0 += ec[(size_t)tc[n * L_ + l] * D_ + d];
    a1 += ep[(size_t)tp[n * L_ + l] * D_ + d];
    a2 += ed[(size_t)td[n * L_ + l] * D_ + d];
  }
  size_t o0 = (size_t)n * D_ + d;
  u16 h;
  h = f2bf(a0); ce_hi[o0] = h;              ce_lo[o0] = f2bf(a0 - bf2f(h));
  h = f2bf(a1); ce_hi[(size_t)N_ * D_ + o0] = h; ce_lo[(size_t)N_ * D_ + o0] = f2bf(a1 - bf2f(h));
  h = f2bf(a2); ce_hi[(size_t)2 * N_ * D_ + o0] = h; ce_lo[(size_t)2 * N_ * D_ + o0] = f2bf(a2 - bf2f(h));
  float w = wv[n], a = av[n];
  float v1 = w * iw[d] + ib[d];
  float v2 = a * iw[D_ + d] + ib[D_ + d];
  h = f2bf(v1); vx_hi[(size_t)5 * N_ * D_ + o0] = h; vx_lo[(size_t)5 * N_ * D_ + o0] = f2bf(v1 - bf2f(h));
  h = f2bf(v2); vx_hi[(size_t)6 * N_ * D_ + o0] = h; vx_lo[(size_t)6 * N_ * D_ + o0] = f2bf(v2 - bf2f(h));
}

// ---------------- Kernel 2: monitor pair embeddings (lab / inj) ----------------
__global__ __launch_bounds__(128) void k_pair_embed(
    const int* __restrict__ tli, const int* __restrict__ tlv,
    const int* __restrict__ tii, const int* __restrict__ tiv,
    const float* __restrict__ eli, const float* __restrict__ elv,
    const float* __restrict__ eii, const float* __restrict__ eiv,
    u16* __restrict__ mx_hi, u16* __restrict__ mx_lo) {
  int r = blockIdx.x, d = threadIdx.x;
  float al = 0.f, ai = 0.f;
#pragma unroll 4
  for (int l = 0; l < L_; l++) {
    al += eli[(size_t)tli[r * L_ + l] * D_ + d] * elv[(size_t)tlv[r * L_ + l] * D_ + d];
    ai += eii[(size_t)tii[r * L_ + l] * D_ + d] * eiv[(size_t)tiv[r * L_ + l] * D_ + d];
  }
  size_t o = (size_t)r * D_ + d;
  u16 h;
  h = f2bf(al); mx_hi[o] = h;                      mx_lo[o] = f2bf(al - bf2f(h));
  h = f2bf(ai); mx_hi[(size_t)NM_ * D_ + o] = h;   mx_lo[(size_t)NM_ * D_ + o] = f2bf(ai - bf2f(h));
}

// ---------------- Kernel 3: xg = A @ W^T + bias, MFMA, hi/lo A and W ----------------
// A: [nkeys][rows][128] bf16 hi/lo.  W: [nkeys][384][128] bf16 hi/lo.  bias f32. out f32.
// grid: (rows/16, 384/64, nkeys), block 256.
__global__ __launch_bounds__(256) void k_gemm_xg(
    const u16* __restrict__ A_hi, const u16* __restrict__ A_lo,
    const u16* __restrict__ W_hi, const u16* __restrict__ W_lo,
    const float* __restrict__ bias,
    float* __restrict__ out, int A_ks, int W_ks, int b_ks, int o_ks) {
  int key = blockIdx.z;
  int wv = threadIdx.x >> 6, lane = threadIdx.x & 63;
  int mn = lane & 15, q = lane >> 4;
  int row0 = blockIdx.x * 16;
  int col0 = blockIdx.y * 64 + wv * 16;
  const u16* Ah = A_hi + (size_t)key * A_ks + (size_t)(row0 + mn) * D_;
  const u16* Al = A_lo + (size_t)key * A_ks + (size_t)(row0 + mn) * D_;
  const u16* Wh = W_hi + (size_t)key * W_ks + (size_t)(col0 + mn) * D_;
  const u16* Wl = W_lo + (size_t)key * W_ks + (size_t)(col0 + mn) * D_;
  floatx4 acc0 = {0.f, 0.f, 0.f, 0.f};
  floatx4 acc1 = {0.f, 0.f, 0.f, 0.f};
  floatx4 acc2 = {0.f, 0.f, 0.f, 0.f};
#pragma unroll
  for (int kk = 0; kk < 4; kk++) {
    int off = kk * 32 + q * 8;
    bf16x8 a_h = *(const bf16x8*)(Ah + off);
    bf16x8 a_l = *(const bf16x8*)(Al + off);
    bf16x8 w_h = *(const bf16x8*)(Wh + off);
    bf16x8 w_l = *(const bf16x8*)(Wl + off);
    acc0 = mfma16(a_h, w_h, acc0);
    acc1 = mfma16(a_l, w_h, acc1);
    acc2 = mfma16(a_h, w_l, acc2);
  }
  int c = col0 + mn;
  float bv = bias[key * b_ks + c];
  float* op = out + (size_t)key * o_ks + (size_t)(row0 + q * 4) * G_ + c;
#pragma unroll
  for (int i = 0; i < 4; i++) op[(size_t)i * G_] = acc0[i] + acc1[i] + acc2[i] + bv;
}

// ---------------- Kernel 4: GRU recurrence ----------------
__global__ __launch_bounds__(256) void k_gru(
    int mode, int cpk, int T,
    const float* __restrict__ xg_a, const float* __restrict__ xg_b,
    const u16* __restrict__ whh_all, const float* __restrict__ bhh_all,
    u16* __restrict__ out_hi, u16* __restrict__ out_lo, float* __restrict__ out_f32) {
  int key = blockIdx.x / cpk;
  int chunk = blockIdx.x % cpk;
  int n0 = chunk * 16;
  const u16* whh = whh_all + (size_t)key * (G_ * D_);
  const float* bhh = bhh_all + (size_t)key * G_;

  __shared__ __align__(16) float gh[16][388];
  __shared__ __align__(16) u16 hhi[16][128];
  __shared__ __align__(16) u16 hlo[16][128];
  __shared__ __align__(16) float bhh_s[G_];

  int tid = threadIdx.x;
  int wv = tid >> 6, lane = tid & 63, mq = lane & 15, q = lane >> 4;

  for (int i = tid; i < 16 * 128; i += 256) { (&hhi[0][0])[i] = 0; (&hlo[0][0])[i] = 0; }
  for (int i = tid; i < G_; i += 256) bhh_s[i] = bhh[i];

  // preload whh fragments: wave wv covers cols [wv*96, wv*96+96)
  int col0w = wv * 96;
  bf16x8 bw[6][4];
#pragma unroll
  for (int j = 0; j < 6; j++)
#pragma unroll
    for (int kk = 0; kk < 4; kk++)
      bw[j][kk] = *(const bf16x8*)(whh + (size_t)(col0w + j * 16 + mq) * D_ + kk * 32 + q * 8);

  int gm = tid >> 4;   // sequence within chunk (0..15)
  int gdb = tid & 15;  // d-block (8 elems each)
  const float* xgp;
  int t_stride;
  if (mode == 0) {
    if (key < 3) { xgp = xg_a + ((size_t)key * N_ + (n0 + gm)) * G_; t_stride = 0; }
    else { xgp = xg_b + ((size_t)(key - 3) * NM_ + (size_t)(n0 + gm) * M_) * G_; t_stride = G_; }
  } else {
    xgp = xg_a + ((size_t)key * N_ + gm * V_) * G_; t_stride = G_;
  }
  __syncthreads();

  for (int t = 0; t < T; t++) {
    // ---- MFMA phase: gh = h @ whh^T ----
    bf16x8 ah[4], al4[4];
#pragma unroll
    for (int kk = 0; kk < 4; kk++) {
      int c = (kk * 4 + q) ^ mq;  // XOR-swizzled chunk
      ah[kk] = *(const bf16x8*)(&hhi[mq][c * 8]);
      al4[kk] = *(const bf16x8*)(&hlo[mq][c * 8]);
    }
#pragma unroll
    for (int j = 0; j < 6; j++) {
      floatx4 acc_h = {0.f, 0.f, 0.f, 0.f};
      floatx4 acc_l = {0.f, 0.f, 0.f, 0.f};
#pragma unroll
      for (int kk = 0; kk < 4; kk++) {
        acc_h = mfma16(ah[kk], bw[j][kk], acc_h);
        acc_l = mfma16(al4[kk], bw[j][kk], acc_l);
      }
      int c = col0w + j * 16 + mq;
#pragma unroll
      for (int i = 0; i < 4; i++) gh[q * 4 + i][c] = acc_h[i] + acc_l[i];
    }
    __syncthreads();

    // ---- gate phase ----
    const float* xr = xgp + (size_t)t * t_stride;
    int d0 = gdb * 8;
    int cc = ((gdb ^ gm) * 8);  // swizzled physical chunk for this thread's h elems
    float h2v[8];
#pragma unroll
    for (int e = 0; e < 8; e++) {
      int d = d0 + e;
      float xrv = xr[d], xzv = xr[128 + d], xnv = xr[256 + d];
      float ghr = gh[gm][d] + bhh_s[d];
      float ghz = gh[gm][128 + d] + bhh_s[128 + d];
      float ghn = gh[gm][256 + d] + bhh_s[256 + d];
      float h = bf2f(hhi[gm][cc + e]) + bf2f(hlo[gm][cc + e]);
      float r = sigm_(xrv + ghr);
      float z = sigm_(xzv + ghz);
      float nn2 = tanh_(xnv + r * ghn);
      h2v[e] = (1.0f - z) * nn2 + z * h;
    }
    if (t == T - 1) {
      if (mode == 0) {
        size_t base = ((size_t)key * N_ + (n0 + gm)) * D_ + d0;
#pragma unroll
        for (int e = 0; e < 8; e++) {
          u16 hb = f2bf(h2v[e]);
          out_hi[base + e] = hb;
          out_lo[base + e] = f2bf(h2v[e] - bf2f(hb));
        }
      } else {
        size_t base = ((size_t)key * 16 + gm) * D_ + d0;
#pragma unroll
        for (int e = 0; e < 8; e++) out_f32[base + e] = h2v[e];
      }
    } else {
#pragma unroll
      for (int e = 0; e < 8; e++) {
        u16 hb = f2bf(h2v[e]);
        hhi[gm][cc + e] = hb;
        hlo[gm][cc + e] = f2bf(h2v[e] - bf2f(hb));
      }
    }
    __syncthreads();
  }
}

// ---------------- Kernel 5: ReLU + FC (f32 output) ----------------
__global__ __launch_bounds__(256) void k_fc(
    const float* __restrict__ vis_h, const float* __restrict__ fc_w,
    const float* __restrict__ fc_b, float* __restrict__ out) {
  int b = blockIdx.x, tid = threadIdx.x;
  __shared__ float hb[7 * D_];
  for (int i = tid; i < 7 * D_; i += 256) {
    int k = i >> 7, d = i & 127;
    float v = vis_h[((size_t)k * 16 + b) * D_ + d];
    hb[i] = v > 0.f ? v : 0.f;
  }
  __syncthreads();
  if (tid < OUT_) {
    float acc = fc_b[tid];
#pragma unroll 8
    for (int i = 0; i < 7 * D_; i++) acc += hb[i] * fc_w[(size_t)i * OUT_ + tid];
    out[(size_t)b * OUT_ + tid] = acc;
  }
}

extern "C" void kernel_launch(void* const* d_in, const int* in_sizes, int n_in,
                              void* d_out, int out_size, void* d_ws, size_t ws_size,
                              hipStream_t stream) {
  (void)in_sizes; (void)n_in; (void)out_size; (void)ws_size;
  const int* tok_cond = (const int*)d_in[0];
  const int* tok_proc = (const int*)d_in[1];
  const int* tok_drug = (const int*)d_in[2];
  const int* tok_lab_item = (const int*)d_in[3];
  const int* tok_lab_value = (const int*)d_in[4];
  const int* tok_inj_item = (const int*)d_in[5];
  const int* tok_inj_value = (const int*)d_in[6];
  const float* weight = (const float*)d_in[7];
  const float* age = (const float*)d_in[8];
  const float* emb_cond = (const float*)d_in[9];
  const float* emb_proc = (const float*)d_in[10];
  const float* emb_drug = (const float*)d_in[11];
  const float* emb_lab_item = (const float*)d_in[12];
  const float* emb_lab_value = (const float*)d_in[13];
  const float* emb_inj_item = (const float*)d_in[14];
  const float* emb_inj_value = (const float*)d_in[15];
  const float* mgru_wih = (const float*)d_in[16];
  const float* mgru_whh = (const float*)d_in[17];
  const float* mgru_bih = (const float*)d_in[18];
  const float* mgru_bhh = (const float*)d_in[19];
  const float* vgru_wih = (const float*)d_in[20];
  const float* vgru_whh = (const float*)d_in[21];
  const float* vgru_bih = (const float*)d_in[22];
  const float* vgru_bhh = (const float*)d_in[23];
  const float* info_w = (const float*)d_in[24];
  const float* info_b = (const float*)d_in[25];
  const float* fc_w = (const float*)d_in[26];
  const float* fc_b = (const float*)d_in[27];

  char* p = (char*)d_ws;
  auto take = [&](size_t bytes) { char* r = p; p += (bytes + 255) & ~(size_t)255; return r; };
  u16* mon_x_hi = (u16*)take((size_t)2 * NM_ * D_ * 2);
  u16* mon_x_lo = (u16*)take((size_t)2 * NM_ * D_ * 2);
  u16* ce_hi = (u16*)take((size_t)3 * N_ * D_ * 2);
  u16* ce_lo = (u16*)take((size_t)3 * N_ * D_ * 2);
  u16* vis_x_hi = (u16*)take((size_t)7 * N_ * D_ * 2);
  u16* vis_x_lo = (u16*)take((size_t)7 * N_ * D_ * 2);
  float* xg_mon = (float*)take((size_t)2 * NM_ * G_ * 4);
  float* xg_c = (float*)take((size_t)3 * N_ * G_ * 4);
  float* xg_v = (float*)take((size_t)7 * N_ * G_ * 4);
  float* vis_h = (float*)take((size_t)7 * 16 * D_ * 4);
  u16* wih_hi = (u16*)take((size_t)12 * G_ * D_ * 2);
  u16* wih_lo = (u16*)take((size_t)12 * G_ * D_ * 2);
  u16* whh_hi = (u16*)take((size_t)12 * G_ * D_ * 2);
  u16* whh_lo = (u16*)take((size_t)12 * G_ * D_ * 2);

  k_conv_w<<<(24 * G_ * D_) / 256, 256, 0, stream>>>(mgru_wih, vgru_wih, mgru_whh, vgru_whh,
                                                     wih_hi, wih_lo, whh_hi, whh_lo);
  k_visit_embed<<<N_, D_, 0, stream>>>(tok_cond, tok_proc, tok_drug, emb_cond, emb_proc, emb_drug,
                                       weight, age, info_w, info_b, ce_hi, ce_lo, vis_x_hi, vis_x_lo);
  k_pair_embed<<<NM_, D_, 0, stream>>>(tok_lab_item, tok_lab_value, tok_inj_item, tok_inj_value,
                                       emb_lab_item, emb_lab_value, emb_inj_item, emb_inj_value,
                                       mon_x_hi, mon_x_lo);
  // xg for lab/inj monitor keys (3,4): rows = 8192 each
  k_gemm_xg<<<dim3(NM_ / 16, 6, 2), 256, 0, stream>>>(
      mon_x_hi, mon_x_lo, wih_hi + (size_t)3 * G_ * D_, wih_lo + (size_t)3 * G_ * D_,
      mgru_bih + 3 * G_, xg_mon, NM_ * D_, G_ * D_, G_, NM_ * G_);
  // xg for time-constant monitor keys (0..2): rows = 256 each
  k_gemm_xg<<<dim3(N_ / 16, 6, 3), 256, 0, stream>>>(
      ce_hi, ce_lo, wih_hi, wih_lo, mgru_bih, xg_c, N_ * D_, G_ * D_, G_, N_ * G_);
  // monitor-level recurrence: 5 keys x 16 chunks, T=32; writes vis_x keys 0..4
  k_gru<<<80, 256, 0, stream>>>(0, 16, 32, xg_c, xg_mon, whh_hi, mgru_bhh,
                                vis_x_hi, vis_x_lo, nullptr);
  // xg for visit keys (0..6): rows = 256 each (row = b*16 + t)
  k_gemm_xg<<<dim3(N_ / 16, 6, 7), 256, 0, stream>>>(
      vis_x_hi, vis_x_lo, wih_hi + (size_t)5 * G_ * D_, wih_lo + (size_t)5 * G_ * D_,
      vgru_bih, xg_v, N_ * D_, G_ * D_, G_, N_ * G_);
  // visit-level recurrence: 7 keys, T=16; writes vis_h f32
  k_gru<<<7, 256, 0, stream>>>(1, 1, 16, xg_v, nullptr, whh_hi + (size_t)5 * G_ * D_, vgru_bhh,
                               nullptr, nullptr, vis_h);
  k_fc<<<B_, 256, 0, stream>>>(vis_h, fc_w, fc_b, (float*)d_out);
}

// Round 4
// 334.119 us; speedup vs baseline: 1.0021x; 1.0021x over previous
//
#include <hip/hip_runtime.h>
#include <stdint.h>

typedef unsigned short u16;
typedef unsigned int u32;

#define B_ 16
#define V_ 16
#define M_ 32
#define L_ 24
#define D_ 128
#define G_ 384   // 3*D
#define N_ 256   // B*V
#define NM_ 8192 // B*V*M
#define OUT_ 193

using bf16x8 = __attribute__((ext_vector_type(8))) __bf16;
using floatx4 = __attribute__((ext_vector_type(4))) float;
using u32x4 = __attribute__((ext_vector_type(4))) u32;

__device__ __forceinline__ float bf2f(u16 u) {
  u32 x = ((u32)u) << 16;
  return __builtin_bit_cast(float, x);
}
__device__ __forceinline__ u16 f2bf(float f) {
  u32 u = __builtin_bit_cast(u32, f);
  u = (u + 0x7FFFu + ((u >> 16) & 1u)) >> 16;
  return (u16)u;
}
__device__ __forceinline__ float sigm_(float x) {
  return 1.0f / (1.0f + __expf(-x));
}
__device__ __forceinline__ float tanh_(float x) {
  float e = __expf(2.0f * x);
  return 1.0f - 2.0f / (e + 1.0f);
}
__device__ __forceinline__ floatx4 mfma16(bf16x8 a, bf16x8 b, floatx4 c) {
  return __builtin_amdgcn_mfma_f32_16x16x32_bf16(a, b, c, 0, 0, 0);
}

// ---------------- Kernel 0: convert f32 GRU weights -> hi/lo bf16 planes ----------------
__global__ __launch_bounds__(256) void k_conv_w(
    const float* __restrict__ mwih, const float* __restrict__ vwih,
    const float* __restrict__ mwhh, const float* __restrict__ vwhh,
    u16* __restrict__ wih_hi, u16* __restrict__ wih_lo,
    u16* __restrict__ whh_hi, u16* __restrict__ whh_lo) {
  const int S5 = 5 * G_ * D_, S12 = 12 * G_ * D_;
  int i = blockIdx.x * 256 + threadIdx.x;
  float v;
  u16 *dh, *dl;
  int o;
  if (i < S12) {
    o = i;
    v = (o < S5) ? mwih[o] : vwih[o - S5];
    dh = wih_hi; dl = wih_lo;
  } else {
    o = i - S12;
    v = (o < S5) ? mwhh[o] : vwhh[o - S5];
    dh = whh_hi; dl = whh_lo;
  }
  u16 h = f2bf(v);
  dh[o] = h;
  dl[o] = f2bf(v - bf2f(h));
}

// ---------------- Kernel 1: visit-event embeddings + info linears ----------------
__global__ __launch_bounds__(128) void k_visit_embed(
    const int* __restrict__ tc, const int* __restrict__ tp, const int* __restrict__ td,
    const float* __restrict__ ec, const float* __restrict__ ep, const float* __restrict__ ed,
    const float* __restrict__ wv, const float* __restrict__ av,
    const float* __restrict__ iw, const float* __restrict__ ib,
    u16* __restrict__ ce_hi, u16* __restrict__ ce_lo,
    u16* __restrict__ vx_hi, u16* __restrict__ vx_lo) {
  int n = blockIdx.x, d = threadIdx.x;
  float a0 = 0.f, a1 = 0.f, a2 = 0.f;
#pragma unroll 4
  for (int l = 0; l < L_; l++) {
    a0 += ec[(size_t)tc[n * L_ + l] * D_ + d];
    a1 += ep[(size_t)tp[n * L_ + l] * D_ + d];
    a2 += ed[(size_t)td[n * L_ + l] * D_ + d];
  }
  size_t o0 = (size_t)n * D_ + d;
  u16 h;
  h = f2bf(a0); ce_hi[o0] = h;              ce_lo[o0] = f2bf(a0 - bf2f(h));
  h = f2bf(a1); ce_hi[(size_t)N_ * D_ + o0] = h; ce_lo[(size_t)N_ * D_ + o0] = f2bf(a1 - bf2f(h));
  h = f2bf(a2); ce_hi[(size_t)2 * N_ * D_ + o0] = h; ce_lo[(size_t)2 * N_ * D_ + o0] = f2bf(a2 - bf2f(h));
  float w = wv[n], a = av[n];
  float v1 = w * iw[d] + ib[d];
  float v2 = a * iw[D_ + d] + ib[D_ + d];
  h = f2bf(v1); vx_hi[(size_t)5 * N_ * D_ + o0] = h; vx_lo[(size_t)5 * N_ * D_ + o0] = f2bf(v1 - bf2f(h));
  h = f2bf(v2); vx_hi[(size_t)6 * N_ * D_ + o0] = h; vx_lo[(size_t)6 * N_ * D_ + o0] = f2bf(v2 - bf2f(h));
}

// ---------------- Kernel 2: monitor pair embeddings (lab / inj) ----------------
__global__ __launch_bounds__(128) void k_pair_embed(
    const int* __restrict__ tli, const int* __restrict__ tlv,
    const int* __restrict__ tii, const int* __restrict__ tiv,
    const float* __restrict__ eli, const float* __restrict__ elv,
    const float* __restrict__ eii, const float* __restrict__ eiv,
    u16* __restrict__ mx_hi, u16* __restrict__ mx_lo) {
  int r = blockIdx.x, d = threadIdx.x;
  float al = 0.f, ai = 0.f;
#pragma unroll 4
  for (int l = 0; l < L_; l++) {
    al += eli[(size_t)tli[r * L_ + l] * D_ + d] * elv[(size_t)tlv[r * L_ + l] * D_ + d];
    ai += eii[(size_t)tii[r * L_ + l] * D_ + d] * eiv[(size_t)tiv[r * L_ + l] * D_ + d];
  }
  size_t o = (size_t)r * D_ + d;
  u16 h;
  h = f2bf(al); mx_hi[o] = h;                      mx_lo[o] = f2bf(al - bf2f(h));
  h = f2bf(ai); mx_hi[(size_t)NM_ * D_ + o] = h;   mx_lo[(size_t)NM_ * D_ + o] = f2bf(ai - bf2f(h));
}

// ---------------- Kernel 3: xg = A @ W^T + bias, MFMA, hi/lo A and W ----------------
__global__ __launch_bounds__(256) void k_gemm_xg(
    const u16* __restrict__ A_hi, const u16* __restrict__ A_lo,
    const u16* __restrict__ W_hi, const u16* __restrict__ W_lo,
    const float* __restrict__ bias,
    float* __restrict__ out, int A_ks, int W_ks, int b_ks, int o_ks) {
  int key = blockIdx.z;
  int wv = threadIdx.x >> 6, lane = threadIdx.x & 63;
  int mn = lane & 15, q = lane >> 4;
  int row0 = blockIdx.x * 16;
  int col0 = blockIdx.y * 64 + wv * 16;
  const u16* Ah = A_hi + (size_t)key * A_ks + (size_t)(row0 + mn) * D_;
  const u16* Al = A_lo + (size_t)key * A_ks + (size_t)(row0 + mn) * D_;
  const u16* Wh = W_hi + (size_t)key * W_ks + (size_t)(col0 + mn) * D_;
  const u16* Wl = W_lo + (size_t)key * W_ks + (size_t)(col0 + mn) * D_;
  floatx4 acc0 = {0.f, 0.f, 0.f, 0.f};
  floatx4 acc1 = {0.f, 0.f, 0.f, 0.f};
  floatx4 acc2 = {0.f, 0.f, 0.f, 0.f};
#pragma unroll
  for (int kk = 0; kk < 4; kk++) {
    int off = kk * 32 + q * 8;
    bf16x8 a_h = *(const bf16x8*)(Ah + off);
    bf16x8 a_l = *(const bf16x8*)(Al + off);
    bf16x8 w_h = *(const bf16x8*)(Wh + off);
    bf16x8 w_l = *(const bf16x8*)(Wl + off);
    acc0 = mfma16(a_h, w_h, acc0);
    acc1 = mfma16(a_l, w_h, acc1);
    acc2 = mfma16(a_h, w_l, acc2);
  }
  int c = col0 + mn;
  float bv = bias[key * b_ks + c];
  float* op = out + (size_t)key * o_ks + (size_t)(row0 + q * 4) * G_ + c;
#pragma unroll
  for (int i = 0; i < 4; i++) op[(size_t)i * G_] = acc0[i] + acc1[i] + acc2[i] + bv;
}

// ---------------- Kernel 4: GRU recurrence (single barrier/step, in-register gates) ----------------
// Wave w owns gh col-tiles {w+4j}: cols 16w+64j, j=0..5 -> j = gate*2 + dgroup.
// Lane (q,mq) owns elements (row=q*4+i, d=16w+mq+64*ab): all 3 gate pre-acts in its own accs.
// h stored in LDS as packed (hi | lo<<16) u32 words, unit(4-word)-XOR-swizzled, ping-pong.
__global__ __launch_bounds__(256, 1) void k_gru(
    int mode, int cpk, int T,
    const float* __restrict__ xg_a, const float* __restrict__ xg_b,
    const u16* __restrict__ whh_all, const float* __restrict__ bhh_all,
    u16* __restrict__ out_hi, u16* __restrict__ out_lo, float* __restrict__ out_f32) {
  int key = blockIdx.x / cpk;
  int chunk = blockIdx.x % cpk;
  int n0 = chunk * 16;
  const u16* whh = whh_all + (size_t)key * (G_ * D_);
  const float* bhh = bhh_all + (size_t)key * G_;

  __shared__ u32 hw[2][16 * 128];

  int tid = threadIdx.x;
  int w = tid >> 6, lane = tid & 63, mq = lane & 15, q = lane >> 4;
  int dA = 16 * w + mq;

  // B fragments: tile j at col 16w + 64j (j = gate*2 + dgroup)
  bf16x8 bw[6][4];
#pragma unroll
  for (int j = 0; j < 6; j++)
#pragma unroll
    for (int kk = 0; kk < 4; kk++)
      bw[j][kk] = *(const bf16x8*)(whh + (size_t)(16 * w + 64 * j + mq) * D_ + kk * 32 + q * 8);

  // bhh regs: [g*2+ab]
  float bias_g[6];
#pragma unroll
  for (int g = 0; g < 3; g++)
#pragma unroll
    for (int ab = 0; ab < 2; ab++) bias_g[g * 2 + ab] = bhh[g * 128 + ab * 64 + dA];

  // xg addressing: row r_i = q*4+i
  const float* xbase;
  size_t RS, TS;
  if (mode == 0) {
    if (key < 3) { xbase = xg_a + ((size_t)key * N_ + n0) * G_; RS = G_; TS = 0; }
    else { xbase = xg_b + ((size_t)(key - 3) * NM_ + (size_t)n0 * M_) * G_; RS = (size_t)M_ * G_; TS = G_; }
  } else {
    xbase = xg_a + (size_t)key * N_ * G_; RS = (size_t)16 * G_; TS = G_;
  }
  const float* rowp[4];
#pragma unroll
  for (int i = 0; i < 4; i++) rowp[i] = xbase + (size_t)(q * 4 + i) * RS;

  float xc[24], xn[24];
#pragma unroll
  for (int i = 0; i < 4; i++)
#pragma unroll
    for (int g = 0; g < 3; g++)
#pragma unroll
      for (int ab = 0; ab < 2; ab++) xc[i * 6 + g * 2 + ab] = rowp[i][g * 128 + ab * 64 + dA];

  float h_old[8];
#pragma unroll
  for (int k = 0; k < 8; k++) h_old[k] = 0.f;

  for (int t = 0; t < T; t++) {
    // prefetch xg for t+1 (clamped; hidden under MFMA+gate work)
    {
      size_t to = (size_t)((t + 1 < T) ? t + 1 : t) * TS;
#pragma unroll
      for (int i = 0; i < 4; i++)
#pragma unroll
        for (int g = 0; g < 3; g++)
#pragma unroll
          for (int ab = 0; ab < 2; ab++) xn[i * 6 + g * 2 + ab] = rowp[i][to + g * 128 + ab * 64 + dA];
    }

    floatx4 acc_h[6], acc_l[6];
#pragma unroll
    for (int j = 0; j < 6; j++) { acc_h[j] = {0.f, 0.f, 0.f, 0.f}; acc_l[j] = {0.f, 0.f, 0.f, 0.f}; }

    if (t > 0) {
      const u32* hr = hw[(t - 1) & 1];
#pragma unroll
      for (int kk = 0; kk < 4; kk++) {
        int u0 = kk * 8 + q * 2;
        int p0 = u0 ^ mq, p1 = (u0 + 1) ^ mq;
        u32x4 Wa = *(const u32x4*)&hr[mq * 128 + p0 * 4];
        u32x4 Wb = *(const u32x4*)&hr[mq * 128 + p1 * 4];
        u32x4 hv, lv;
        hv[0] = __builtin_amdgcn_perm(Wa[1], Wa[0], 0x05040100u);
        hv[1] = __builtin_amdgcn_perm(Wa[3], Wa[2], 0x05040100u);
        hv[2] = __builtin_amdgcn_perm(Wb[1], Wb[0], 0x05040100u);
        hv[3] = __builtin_amdgcn_perm(Wb[3], Wb[2], 0x05040100u);
        lv[0] = __builtin_amdgcn_perm(Wa[1], Wa[0], 0x07060302u);
        lv[1] = __builtin_amdgcn_perm(Wa[3], Wa[2], 0x07060302u);
        lv[2] = __builtin_amdgcn_perm(Wb[1], Wb[0], 0x07060302u);
        lv[3] = __builtin_amdgcn_perm(Wb[3], Wb[2], 0x07060302u);
        bf16x8 ah = __builtin_bit_cast(bf16x8, hv);
        bf16x8 al = __builtin_bit_cast(bf16x8, lv);
#pragma unroll
        for (int j = 0; j < 6; j++) {
          acc_h[j] = mfma16(ah, bw[j][kk], acc_h[j]);
          acc_l[j] = mfma16(al, bw[j][kk], acc_l[j]);
        }
      }
    }

    // gate phase — fully in-register
    u32* hwr = hw[t & 1];
    bool last = (t == T - 1);
#pragma unroll
    for (int i = 0; i < 4; i++) {
      int row = q * 4 + i;
#pragma unroll
      for (int ab = 0; ab < 2; ab++) {
        float ghr = acc_h[0 + ab][i] + acc_l[0 + ab][i] + bias_g[0 + ab];
        float ghz = acc_h[2 + ab][i] + acc_l[2 + ab][i] + bias_g[2 + ab];
        float ghn = acc_h[4 + ab][i] + acc_l[4 + ab][i] + bias_g[4 + ab];
        float xr = xc[i * 6 + 0 + ab], xz = xc[i * 6 + 2 + ab], xnn = xc[i * 6 + 4 + ab];
        float r = sigm_(xr + ghr);
        float z = sigm_(xz + ghz);
        float nn = tanh_(xnn + r * ghn);
        float h2 = (1.0f - z) * nn + z * h_old[i * 2 + ab];
        h_old[i * 2 + ab] = h2;
        u16 hb = f2bf(h2);
        u16 lb = f2bf(h2 - bf2f(hb));
        int d = dA + ab * 64;
        if (last) {
          if (mode == 0) {
            size_t o = ((size_t)key * N_ + n0 + row) * D_ + d;
            out_hi[o] = hb;
            out_lo[o] = lb;
          } else {
            out_f32[((size_t)key * 16 + row) * D_ + d] = h2;
          }
        } else {
          hwr[row * 128 + (((d >> 2) ^ row) * 4) + (d & 3)] = (u32)hb | ((u32)lb << 16);
        }
      }
    }
#pragma unroll
    for (int k = 0; k < 24; k++) xc[k] = xn[k];
    __syncthreads();
  }
}

// ---------------- Kernel 5: ReLU + FC (f32 output) ----------------
__global__ __launch_bounds__(256) void k_fc(
    const float* __restrict__ vis_h, const float* __restrict__ fc_w,
    const float* __restrict__ fc_b, float* __restrict__ out) {
  int b = blockIdx.x, tid = threadIdx.x;
  __shared__ float hb[7 * D_];
  for (int i = tid; i < 7 * D_; i += 256) {
    int k = i >> 7, d = i & 127;
    float v = vis_h[((size_t)k * 16 + b) * D_ + d];
    hb[i] = v > 0.f ? v : 0.f;
  }
  __syncthreads();
  if (tid < OUT_) {
    float acc = fc_b[tid];
#pragma unroll 8
    for (int i = 0; i < 7 * D_; i++) acc += hb[i] * fc_w[(size_t)i * OUT_ + tid];
    out[(size_t)b * OUT_ + tid] = acc;
  }
}

extern "C" void kernel_launch(void* const* d_in, const int* in_sizes, int n_in,
                              void* d_out, int out_size, void* d_ws, size_t ws_size,
                              hipStream_t stream) {
  (void)in_sizes; (void)n_in; (void)out_size; (void)ws_size;
  const int* tok_cond = (const int*)d_in[0];
  const int* tok_proc = (const int*)d_in[1];
  const int* tok_drug = (const int*)d_in[2];
  const int* tok_lab_item = (const int*)d_in[3];
  const int* tok_lab_value = (const int*)d_in[4];
  const int* tok_inj_item = (const int*)d_in[5];
  const int* tok_inj_value = (const int*)d_in[6];
  const float* weight = (const float*)d_in[7];
  const float* age = (const float*)d_in[8];
  const float* emb_cond = (const float*)d_in[9];
  const float* emb_proc = (const float*)d_in[10];
  const float* emb_drug = (const float*)d_in[11];
  const float* emb_lab_item = (const float*)d_in[12];
  const float* emb_lab_value = (const float*)d_in[13];
  const float* emb_inj_item = (const float*)d_in[14];
  const float* emb_inj_value = (const float*)d_in[15];
  const float* mgru_wih = (const float*)d_in[16];
  const float* mgru_whh = (const float*)d_in[17];
  const float* mgru_bih = (const float*)d_in[18];
  const float* mgru_bhh = (const float*)d_in[19];
  const float* vgru_wih = (const float*)d_in[20];
  const float* vgru_whh = (const float*)d_in[21];
  const float* vgru_bih = (const float*)d_in[22];
  const float* vgru_bhh = (const float*)d_in[23];
  const float* info_w = (const float*)d_in[24];
  const float* info_b = (const float*)d_in[25];
  const float* fc_w = (const float*)d_in[26];
  const float* fc_b = (const float*)d_in[27];

  char* p = (char*)d_ws;
  auto take = [&](size_t bytes) { char* r = p; p += (bytes + 255) & ~(size_t)255; return r; };
  u16* mon_x_hi = (u16*)take((size_t)2 * NM_ * D_ * 2);
  u16* mon_x_lo = (u16*)take((size_t)2 * NM_ * D_ * 2);
  u16* ce_hi = (u16*)take((size_t)3 * N_ * D_ * 2);
  u16* ce_lo = (u16*)take((size_t)3 * N_ * D_ * 2);
  u16* vis_x_hi = (u16*)take((size_t)7 * N_ * D_ * 2);
  u16* vis_x_lo = (u16*)take((size_t)7 * N_ * D_ * 2);
  float* xg_mon = (float*)take((size_t)2 * NM_ * G_ * 4);
  float* xg_c = (float*)take((size_t)3 * N_ * G_ * 4);
  float* xg_v = (float*)take((size_t)7 * N_ * G_ * 4);
  float* vis_h = (float*)take((size_t)7 * 16 * D_ * 4);
  u16* wih_hi = (u16*)take((size_t)12 * G_ * D_ * 2);
  u16* wih_lo = (u16*)take((size_t)12 * G_ * D_ * 2);
  u16* whh_hi = (u16*)take((size_t)12 * G_ * D_ * 2);
  u16* whh_lo = (u16*)take((size_t)12 * G_ * D_ * 2);

  k_conv_w<<<(24 * G_ * D_) / 256, 256, 0, stream>>>(mgru_wih, vgru_wih, mgru_whh, vgru_whh,
                                                     wih_hi, wih_lo, whh_hi, whh_lo);
  k_visit_embed<<<N_, D_, 0, stream>>>(tok_cond, tok_proc, tok_drug, emb_cond, emb_proc, emb_drug,
                                       weight, age, info_w, info_b, ce_hi, ce_lo, vis_x_hi, vis_x_lo);
  k_pair_embed<<<NM_, D_, 0, stream>>>(tok_lab_item, tok_lab_value, tok_inj_item, tok_inj_value,
                                       emb_lab_item, emb_lab_value, emb_inj_item, emb_inj_value,
                                       mon_x_hi, mon_x_lo);
  k_gemm_xg<<<dim3(NM_ / 16, 6, 2), 256, 0, stream>>>(
      mon_x_hi, mon_x_lo, wih_hi + (size_t)3 * G_ * D_, wih_lo + (size_t)3 * G_ * D_,
      mgru_bih + 3 * G_, xg_mon, NM_ * D_, G_ * D_, G_, NM_ * G_);
  k_gemm_xg<<<dim3(N_ / 16, 6, 3), 256, 0, stream>>>(
      ce_hi, ce_lo, wih_hi, wih_lo, mgru_bih, xg_c, N_ * D_, G_ * D_, G_, N_ * G_);
  k_gru<<<80, 256, 0, stream>>>(0, 16, 32, xg_c, xg_mon, whh_hi, mgru_bhh,
                                vis_x_hi, vis_x_lo, nullptr);
  k_gemm_xg<<<dim3(N_ / 16, 6, 7), 256, 0, stream>>>(
      vis_x_hi, vis_x_lo, wih_hi + (size_t)5 * G_ * D_, wih_lo + (size_t)5 * G_ * D_,
      vgru_bih, xg_v, N_ * D_, G_ * D_, G_, N_ * G_);
  k_gru<<<7, 256, 0, stream>>>(1, 1, 16, xg_v, nullptr, whh_hi + (size_t)5 * G_ * D_, vgru_bhh,
                               nullptr, nullptr, vis_h);
  k_fc<<<B_, 256, 0, stream>>>(vis_h, fc_w, fc_b, (float*)d_out);
}

// Round 5
// 310.447 us; speedup vs baseline: 1.0785x; 1.0763x over previous
//
#include <hip/hip_runtime.h>
#include <stdint.h>

typedef unsigned short u16;
typedef unsigned int u32;

#define B_ 16
#define V_ 16
#define M_ 32
#define L_ 24
#define D_ 128
#define G_ 384   // 3*D
#define N_ 256   // B*V
#define NM_ 8192 // B*V*M
#define OUT_ 193

using bf16x8 = __attribute__((ext_vector_type(8))) __bf16;
using floatx4 = __attribute__((ext_vector_type(4))) float;
using u32x4 = __attribute__((ext_vector_type(4))) u32;

__device__ __forceinline__ float bf2f(u16 u) {
  u32 x = ((u32)u) << 16;
  return __builtin_bit_cast(float, x);
}
__device__ __forceinline__ u16 f2bf(float f) {
  u32 u = __builtin_bit_cast(u32, f);
  u = (u + 0x7FFFu + ((u >> 16) & 1u)) >> 16;
  return (u16)u;
}
__device__ __forceinline__ float sigm_(float x) {
  return __builtin_amdgcn_rcpf(1.0f + __expf(-x));
}
__device__ __forceinline__ float tanh_(float x) {
  float e = __expf(2.0f * x);
  return 1.0f - 2.0f * __builtin_amdgcn_rcpf(e + 1.0f);
}
__device__ __forceinline__ floatx4 mfma16(bf16x8 a, bf16x8 b, floatx4 c) {
  return __builtin_amdgcn_mfma_f32_16x16x32_bf16(a, b, c, 0, 0, 0);
}
// LDS-only barrier: drains lgkmcnt but leaves global loads (vmcnt) in flight.
// __syncthreads() would emit s_waitcnt vmcnt(0) and kill cross-step prefetch.
__device__ __forceinline__ void lds_barrier() {
  asm volatile("s_waitcnt lgkmcnt(0)\n\ts_barrier" ::: "memory");
}

// ---------------- Kernel 0: convert f32 GRU weights -> hi/lo bf16 planes ----------------
__global__ __launch_bounds__(256) void k_conv_w(
    const float* __restrict__ mwih, const float* __restrict__ vwih,
    const float* __restrict__ mwhh, const float* __restrict__ vwhh,
    u16* __restrict__ wih_hi, u16* __restrict__ wih_lo,
    u16* __restrict__ whh_hi, u16* __restrict__ whh_lo) {
  const int S5 = 5 * G_ * D_, S12 = 12 * G_ * D_;
  int i = blockIdx.x * 256 + threadIdx.x;
  float v;
  u16 *dh, *dl;
  int o;
  if (i < S12) {
    o = i;
    v = (o < S5) ? mwih[o] : vwih[o - S5];
    dh = wih_hi; dl = wih_lo;
  } else {
    o = i - S12;
    v = (o < S5) ? mwhh[o] : vwhh[o - S5];
    dh = whh_hi; dl = whh_lo;
  }
  u16 h = f2bf(v);
  dh[o] = h;
  dl[o] = f2bf(v - bf2f(h));
}

// ---------------- Kernel 1: visit-event embeddings + info linears ----------------
__global__ __launch_bounds__(128) void k_visit_embed(
    const int* __restrict__ tc, const int* __restrict__ tp, const int* __restrict__ td,
    const float* __restrict__ ec, const float* __restrict__ ep, const float* __restrict__ ed,
    const float* __restrict__ wv, const float* __restrict__ av,
    const float* __restrict__ iw, const float* __restrict__ ib,
    u16* __restrict__ ce_hi, u16* __restrict__ ce_lo,
    u16* __restrict__ vx_hi, u16* __restrict__ vx_lo) {
  int n = blockIdx.x, d = threadIdx.x;
  float a0 = 0.f, a1 = 0.f, a2 = 0.f;
#pragma unroll 4
  for (int l = 0; l < L_; l++) {
    a0 += ec[(size_t)tc[n * L_ + l] * D_ + d];
    a1 += ep[(size_t)tp[n * L_ + l] * D_ + d];
    a2 += ed[(size_t)td[n * L_ + l] * D_ + d];
  }
  size_t o0 = (size_t)n * D_ + d;
  u16 h;
  h = f2bf(a0); ce_hi[o0] = h;              ce_lo[o0] = f2bf(a0 - bf2f(h));
  h = f2bf(a1); ce_hi[(size_t)N_ * D_ + o0] = h; ce_lo[(size_t)N_ * D_ + o0] = f2bf(a1 - bf2f(h));
  h = f2bf(a2); ce_hi[(size_t)2 * N_ * D_ + o0] = h; ce_lo[(size_t)2 * N_ * D_ + o0] = f2bf(a2 - bf2f(h));
  float w = wv[n], a = av[n];
  float v1 = w * iw[d] + ib[d];
  float v2 = a * iw[D_ + d] + ib[D_ + d];
  h = f2bf(v1); vx_hi[(size_t)5 * N_ * D_ + o0] = h; vx_lo[(size_t)5 * N_ * D_ + o0] = f2bf(v1 - bf2f(h));
  h = f2bf(v2); vx_hi[(size_t)6 * N_ * D_ + o0] = h; vx_lo[(size_t)6 * N_ * D_ + o0] = f2bf(v2 - bf2f(h));
}

// ---------------- Kernel 2: monitor pair embeddings (lab / inj) ----------------
__global__ __launch_bounds__(128) void k_pair_embed(
    const int* __restrict__ tli, const int* __restrict__ tlv,
    const int* __restrict__ tii, const int* __restrict__ tiv,
    const float* __restrict__ eli, const float* __restrict__ elv,
    const float* __restrict__ eii, const float* __restrict__ eiv,
    u16* __restrict__ mx_hi, u16* __restrict__ mx_lo) {
  int r = blockIdx.x, d = threadIdx.x;
  float al = 0.f, ai = 0.f;
#pragma unroll 4
  for (int l = 0; l < L_; l++) {
    al += eli[(size_t)tli[r * L_ + l] * D_ + d] * elv[(size_t)tlv[r * L_ + l] * D_ + d];
    ai += eii[(size_t)tii[r * L_ + l] * D_ + d] * eiv[(size_t)tiv[r * L_ + l] * D_ + d];
  }
  size_t o = (size_t)r * D_ + d;
  u16 h;
  h = f2bf(al); mx_hi[o] = h;                      mx_lo[o] = f2bf(al - bf2f(h));
  h = f2bf(ai); mx_hi[(size_t)NM_ * D_ + o] = h;   mx_lo[(size_t)NM_ * D_ + o] = f2bf(ai - bf2f(h));
}

// ---------------- Kernel 3: xg = A @ W^T + bias, MFMA, hi/lo A and W ----------------
__global__ __launch_bounds__(256) void k_gemm_xg(
    const u16* __restrict__ A_hi, const u16* __restrict__ A_lo,
    const u16* __restrict__ W_hi, const u16* __restrict__ W_lo,
    const float* __restrict__ bias,
    float* __restrict__ out, int A_ks, int W_ks, int b_ks, int o_ks) {
  int key = blockIdx.z;
  int wv = threadIdx.x >> 6, lane = threadIdx.x & 63;
  int mn = lane & 15, q = lane >> 4;
  int row0 = blockIdx.x * 16;
  int col0 = blockIdx.y * 64 + wv * 16;
  const u16* Ah = A_hi + (size_t)key * A_ks + (size_t)(row0 + mn) * D_;
  const u16* Al = A_lo + (size_t)key * A_ks + (size_t)(row0 + mn) * D_;
  const u16* Wh = W_hi + (size_t)key * W_ks + (size_t)(col0 + mn) * D_;
  const u16* Wl = W_lo + (size_t)key * W_ks + (size_t)(col0 + mn) * D_;
  floatx4 acc0 = {0.f, 0.f, 0.f, 0.f};
  floatx4 acc1 = {0.f, 0.f, 0.f, 0.f};
  floatx4 acc2 = {0.f, 0.f, 0.f, 0.f};
#pragma unroll
  for (int kk = 0; kk < 4; kk++) {
    int off = kk * 32 + q * 8;
    bf16x8 a_h = *(const bf16x8*)(Ah + off);
    bf16x8 a_l = *(const bf16x8*)(Al + off);
    bf16x8 w_h = *(const bf16x8*)(Wh + off);
    bf16x8 w_l = *(const bf16x8*)(Wl + off);
    acc0 = mfma16(a_h, w_h, acc0);
    acc1 = mfma16(a_l, w_h, acc1);
    acc2 = mfma16(a_h, w_l, acc2);
  }
  int c = col0 + mn;
  float bv = bias[key * b_ks + c];
  float* op = out + (size_t)key * o_ks + (size_t)(row0 + q * 4) * G_ + c;
#pragma unroll
  for (int i = 0; i < 4; i++) op[(size_t)i * G_] = acc0[i] + acc1[i] + acc2[i] + bv;
}

// ---------------- Kernel 4: GRU recurrence ----------------
// One LDS-only barrier per step (raw s_barrier + lgkmcnt drain); xg prefetched
// depth-2 in registers so global-load latency spans a full step and survives
// the barrier (vmcnt never force-drained inside the loop).
__global__ __launch_bounds__(256, 1) void k_gru(
    int mode, int cpk, int T,
    const float* __restrict__ xg_a, const float* __restrict__ xg_b,
    const u16* __restrict__ whh_all, const float* __restrict__ bhh_all,
    u16* __restrict__ out_hi, u16* __restrict__ out_lo, float* __restrict__ out_f32) {
  int key = blockIdx.x / cpk;
  int chunk = blockIdx.x % cpk;
  int n0 = chunk * 16;
  const u16* whh = whh_all + (size_t)key * (G_ * D_);
  const float* bhh = bhh_all + (size_t)key * G_;

  __shared__ u32 hw[2][16 * 128];

  int tid = threadIdx.x;
  int w = tid >> 6, lane = tid & 63, mq = lane & 15, q = lane >> 4;
  int dA = 16 * w + mq;

  // B fragments: tile j at col 16w + 64j (j = gate*2 + dgroup)
  bf16x8 bw[6][4];
#pragma unroll
  for (int j = 0; j < 6; j++)
#pragma unroll
    for (int kk = 0; kk < 4; kk++)
      bw[j][kk] = *(const bf16x8*)(whh + (size_t)(16 * w + 64 * j + mq) * D_ + kk * 32 + q * 8);

  float bias_g[6];
#pragma unroll
  for (int g = 0; g < 3; g++)
#pragma unroll
    for (int ab = 0; ab < 2; ab++) bias_g[g * 2 + ab] = bhh[g * 128 + ab * 64 + dA];

  const float* xbase;
  size_t RS, TS;
  if (mode == 0) {
    if (key < 3) { xbase = xg_a + ((size_t)key * N_ + n0) * G_; RS = G_; TS = 0; }
    else { xbase = xg_b + ((size_t)(key - 3) * NM_ + (size_t)n0 * M_) * G_; RS = (size_t)M_ * G_; TS = G_; }
  } else {
    xbase = xg_a + (size_t)key * N_ * G_; RS = (size_t)16 * G_; TS = G_;
  }
  const float* rowp[4];
#pragma unroll
  for (int i = 0; i < 4; i++) rowp[i] = xbase + (size_t)(q * 4 + i) * RS;

  // depth-2 rotating prefetch streams: xc = step t, xm = t+1, xf = t+2
  float xc[24], xm[24], xf[24];
#pragma unroll
  for (int i = 0; i < 4; i++)
#pragma unroll
    for (int g = 0; g < 3; g++)
#pragma unroll
      for (int ab = 0; ab < 2; ab++) {
        xc[i * 6 + g * 2 + ab] = rowp[i][g * 128 + ab * 64 + dA];
        xm[i * 6 + g * 2 + ab] = rowp[i][(size_t)(T > 1 ? 1 : 0) * TS + g * 128 + ab * 64 + dA];
      }

  float h_old[8];
#pragma unroll
  for (int k = 0; k < 8; k++) h_old[k] = 0.f;

  for (int t = 0; t < T; t++) {
    // prefetch xg for t+2 (clamped) — consumed two steps later
    {
      int tf = t + 2 < T ? t + 2 : T - 1;
      size_t to = (size_t)tf * TS;
#pragma unroll
      for (int i = 0; i < 4; i++)
#pragma unroll
        for (int g = 0; g < 3; g++)
#pragma unroll
          for (int ab = 0; ab < 2; ab++) xf[i * 6 + g * 2 + ab] = rowp[i][to + g * 128 + ab * 64 + dA];
    }

    floatx4 acc_h[6], acc_l[6];
#pragma unroll
    for (int j = 0; j < 6; j++) { acc_h[j] = {0.f, 0.f, 0.f, 0.f}; acc_l[j] = {0.f, 0.f, 0.f, 0.f}; }

    if (t > 0) {
      const u32* hr = hw[(t - 1) & 1];
#pragma unroll
      for (int kk = 0; kk < 4; kk++) {
        int u0 = kk * 8 + q * 2;
        int p0 = u0 ^ mq, p1 = (u0 + 1) ^ mq;
        u32x4 Wa = *(const u32x4*)&hr[mq * 128 + p0 * 4];
        u32x4 Wb = *(const u32x4*)&hr[mq * 128 + p1 * 4];
        u32x4 hv, lv;
        hv[0] = __builtin_amdgcn_perm(Wa[1], Wa[0], 0x05040100u);
        hv[1] = __builtin_amdgcn_perm(Wa[3], Wa[2], 0x05040100u);
        hv[2] = __builtin_amdgcn_perm(Wb[1], Wb[0], 0x05040100u);
        hv[3] = __builtin_amdgcn_perm(Wb[3], Wb[2], 0x05040100u);
        lv[0] = __builtin_amdgcn_perm(Wa[1], Wa[0], 0x07060302u);
        lv[1] = __builtin_amdgcn_perm(Wa[3], Wa[2], 0x07060302u);
        lv[2] = __builtin_amdgcn_perm(Wb[1], Wb[0], 0x07060302u);
        lv[3] = __builtin_amdgcn_perm(Wb[3], Wb[2], 0x07060302u);
        bf16x8 ah = __builtin_bit_cast(bf16x8, hv);
        bf16x8 al = __builtin_bit_cast(bf16x8, lv);
#pragma unroll
        for (int j = 0; j < 6; j++) {
          acc_h[j] = mfma16(ah, bw[j][kk], acc_h[j]);
          acc_l[j] = mfma16(al, bw[j][kk], acc_l[j]);
        }
      }
    }

    // gate phase — fully in-register
    u32* hwr = hw[t & 1];
    bool last = (t == T - 1);
#pragma unroll
    for (int i = 0; i < 4; i++) {
      int row = q * 4 + i;
#pragma unroll
      for (int ab = 0; ab < 2; ab++) {
        float ghr = acc_h[0 + ab][i] + acc_l[0 + ab][i] + bias_g[0 + ab];
        float ghz = acc_h[2 + ab][i] + acc_l[2 + ab][i] + bias_g[2 + ab];
        float ghn = acc_h[4 + ab][i] + acc_l[4 + ab][i] + bias_g[4 + ab];
        float xr = xc[i * 6 + 0 + ab], xz = xc[i * 6 + 2 + ab], xnn = xc[i * 6 + 4 + ab];
        float r = sigm_(xr + ghr);
        float z = sigm_(xz + ghz);
        float nn = tanh_(xnn + r * ghn);
        float h2 = (1.0f - z) * nn + z * h_old[i * 2 + ab];
        h_old[i * 2 + ab] = h2;
        u16 hb = f2bf(h2);
        u16 lb = f2bf(h2 - bf2f(hb));
        int d = dA + ab * 64;
        if (last) {
          if (mode == 0) {
            size_t o = ((size_t)key * N_ + n0 + row) * D_ + d;
            out_hi[o] = hb;
            out_lo[o] = lb;
          } else {
            out_f32[((size_t)key * 16 + row) * D_ + d] = h2;
          }
        } else {
          hwr[row * 128 + (((d >> 2) ^ row) * 4) + (d & 3)] = (u32)hb | ((u32)lb << 16);
        }
      }
    }
#pragma unroll
    for (int k = 0; k < 24; k++) { xc[k] = xm[k]; xm[k] = xf[k]; }
    lds_barrier();
  }
}

// ---------------- Kernel 5: ReLU + FC (f32 output) ----------------
__global__ __launch_bounds__(256) void k_fc(
    const float* __restrict__ vis_h, const float* __restrict__ fc_w,
    const float* __restrict__ fc_b, float* __restrict__ out) {
  int b = blockIdx.x, tid = threadIdx.x;
  __shared__ float hb[7 * D_];
  for (int i = tid; i < 7 * D_; i += 256) {
    int k = i >> 7, d = i & 127;
    float v = vis_h[((size_t)k * 16 + b) * D_ + d];
    hb[i] = v > 0.f ? v : 0.f;
  }
  __syncthreads();
  if (tid < OUT_) {
    float acc = fc_b[tid];
#pragma unroll 8
    for (int i = 0; i < 7 * D_; i++) acc += hb[i] * fc_w[(size_t)i * OUT_ + tid];
    out[(size_t)b * OUT_ + tid] = acc;
  }
}

extern "C" void kernel_launch(void* const* d_in, const int* in_sizes, int n_in,
                              void* d_out, int out_size, void* d_ws, size_t ws_size,
                              hipStream_t stream) {
  (void)in_sizes; (void)n_in; (void)out_size; (void)ws_size;
  const int* tok_cond = (const int*)d_in[0];
  const int* tok_proc = (const int*)d_in[1];
  const int* tok_drug = (const int*)d_in[2];
  const int* tok_lab_item = (const int*)d_in[3];
  const int* tok_lab_value = (const int*)d_in[4];
  const int* tok_inj_item = (const int*)d_in[5];
  const int* tok_inj_value = (const int*)d_in[6];
  const float* weight = (const float*)d_in[7];
  const float* age = (const float*)d_in[8];
  const float* emb_cond = (const float*)d_in[9];
  const float* emb_proc = (const float*)d_in[10];
  const float* emb_drug = (const float*)d_in[11];
  const float* emb_lab_item = (const float*)d_in[12];
  const float* emb_lab_value = (const float*)d_in[13];
  const float* emb_inj_item = (const float*)d_in[14];
  const float* emb_inj_value = (const float*)d_in[15];
  const float* mgru_wih = (const float*)d_in[16];
  const float* mgru_whh = (const float*)d_in[17];
  const float* mgru_bih = (const float*)d_in[18];
  const float* mgru_bhh = (const float*)d_in[19];
  const float* vgru_wih = (const float*)d_in[20];
  const float* vgru_whh = (const float*)d_in[21];
  const float* vgru_bih = (const float*)d_in[22];
  const float* vgru_bhh = (const float*)d_in[23];
  const float* info_w = (const float*)d_in[24];
  const float* info_b = (const float*)d_in[25];
  const float* fc_w = (const float*)d_in[26];
  const float* fc_b = (const float*)d_in[27];

  char* p = (char*)d_ws;
  auto take = [&](size_t bytes) { char* r = p; p += (bytes + 255) & ~(size_t)255; return r; };
  u16* mon_x_hi = (u16*)take((size_t)2 * NM_ * D_ * 2);
  u16* mon_x_lo = (u16*)take((size_t)2 * NM_ * D_ * 2);
  u16* ce_hi = (u16*)take((size_t)3 * N_ * D_ * 2);
  u16* ce_lo = (u16*)take((size_t)3 * N_ * D_ * 2);
  u16* vis_x_hi = (u16*)take((size_t)7 * N_ * D_ * 2);
  u16* vis_x_lo = (u16*)take((size_t)7 * N_ * D_ * 2);
  float* xg_mon = (float*)take((size_t)2 * NM_ * G_ * 4);
  float* xg_c = (float*)take((size_t)3 * N_ * G_ * 4);
  float* xg_v = (float*)take((size_t)7 * N_ * G_ * 4);
  float* vis_h = (float*)take((size_t)7 * 16 * D_ * 4);
  u16* wih_hi = (u16*)take((size_t)12 * G_ * D_ * 2);
  u16* wih_lo = (u16*)take((size_t)12 * G_ * D_ * 2);
  u16* whh_hi = (u16*)take((size_t)12 * G_ * D_ * 2);
  u16* whh_lo = (u16*)take((size_t)12 * G_ * D_ * 2);

  k_conv_w<<<(24 * G_ * D_) / 256, 256, 0, stream>>>(mgru_wih, vgru_wih, mgru_whh, vgru_whh,
                                                     wih_hi, wih_lo, whh_hi, whh_lo);
  k_visit_embed<<<N_, D_, 0, stream>>>(tok_cond, tok_proc, tok_drug, emb_cond, emb_proc, emb_drug,
                                       weight, age, info_w, info_b, ce_hi, ce_lo, vis_x_hi, vis_x_lo);
  k_pair_embed<<<NM_, D_, 0, stream>>>(tok_lab_item, tok_lab_value, tok_inj_item, tok_inj_value,
                                       emb_lab_item, emb_lab_value, emb_inj_item, emb_inj_value,
                                       mon_x_hi, mon_x_lo);
  k_gemm_xg<<<dim3(NM_ / 16, 6, 2), 256, 0, stream>>>(
      mon_x_hi, mon_x_lo, wih_hi + (size_t)3 * G_ * D_, wih_lo + (size_t)3 * G_ * D_,
      mgru_bih + 3 * G_, xg_mon, NM_ * D_, G_ * D_, G_, NM_ * G_);
  k_gemm_xg<<<dim3(N_ / 16, 6, 3), 256, 0, stream>>>(
      ce_hi, ce_lo, wih_hi, wih_lo, mgru_bih, xg_c, N_ * D_, G_ * D_, G_, N_ * G_);
  k_gru<<<80, 256, 0, stream>>>(0, 16, 32, xg_c, xg_mon, whh_hi, mgru_bhh,
                                vis_x_hi, vis_x_lo, nullptr);
  k_gemm_xg<<<dim3(N_ / 16, 6, 7), 256, 0, stream>>>(
      vis_x_hi, vis_x_lo, wih_hi + (size_t)5 * G_ * D_, wih_lo + (size_t)5 * G_ * D_,
      vgru_bih, xg_v, N_ * D_, G_ * D_, G_, N_ * G_);
  k_gru<<<7, 256, 0, stream>>>(1, 1, 16, xg_v, nullptr, whh_hi + (size_t)5 * G_ * D_, vgru_bhh,
                               nullptr, nullptr, vis_h);
  k_fc<<<B_, 256, 0, stream>>>(vis_h, fc_w, fc_b, (float*)d_out);
}

// Round 6
// 296.195 us; speedup vs baseline: 1.1304x; 1.0481x over previous
//
#include <hip/hip_runtime.h>
#include <stdint.h>

typedef unsigned short u16;
typedef unsigned int u32;

#define B_ 16
#define V_ 16
#define M_ 32
#define L_ 24
#define D_ 128
#define G_ 384   // 3*D
#define N_ 256   // B*V
#define NM_ 8192 // B*V*M
#define OUT_ 193

using bf16x8 = __attribute__((ext_vector_type(8))) __bf16;
using floatx4 = __attribute__((ext_vector_type(4))) float;

__device__ __forceinline__ float bf2f(u16 u) {
  u32 x = ((u32)u) << 16;
  return __builtin_bit_cast(float, x);
}
__device__ __forceinline__ u16 f2bf(float f) {
  u32 u = __builtin_bit_cast(u32, f);
  u = (u + 0x7FFFu + ((u >> 16) & 1u)) >> 16;
  return (u16)u;
}
__device__ __forceinline__ float sigm_(float x) {
  return __builtin_amdgcn_rcpf(1.0f + __expf(-x));
}
__device__ __forceinline__ float tanh_(float x) {
  float e = __expf(2.0f * x);
  return 1.0f - 2.0f * __builtin_amdgcn_rcpf(e + 1.0f);
}
__device__ __forceinline__ floatx4 mfma16(bf16x8 a, bf16x8 b, floatx4 c) {
  return __builtin_amdgcn_mfma_f32_16x16x32_bf16(a, b, c, 0, 0, 0);
}
// LDS-only barrier: drains lgkmcnt but leaves global loads (vmcnt) in flight.
__device__ __forceinline__ void lds_barrier() {
  asm volatile("s_waitcnt lgkmcnt(0)\n\ts_barrier" ::: "memory");
}

// ---------------- Kernel 0: convert f32 GRU weights -> hi/lo bf16 planes ----------------
__global__ __launch_bounds__(256) void k_conv_w(
    const float* __restrict__ mwih, const float* __restrict__ vwih,
    const float* __restrict__ mwhh, const float* __restrict__ vwhh,
    u16* __restrict__ wih_hi, u16* __restrict__ wih_lo,
    u16* __restrict__ whh_hi, u16* __restrict__ whh_lo) {
  const int S5 = 5 * G_ * D_, S12 = 12 * G_ * D_;
  int i = blockIdx.x * 256 + threadIdx.x;
  float v;
  u16 *dh, *dl;
  int o;
  if (i < S12) {
    o = i;
    v = (o < S5) ? mwih[o] : vwih[o - S5];
    dh = wih_hi; dl = wih_lo;
  } else {
    o = i - S12;
    v = (o < S5) ? mwhh[o] : vwhh[o - S5];
    dh = whh_hi; dl = whh_lo;
  }
  u16 h = f2bf(v);
  dh[o] = h;
  dl[o] = f2bf(v - bf2f(h));
}

// ---------------- Kernel 1: visit-event embeddings + info linears ----------------
__global__ __launch_bounds__(128) void k_visit_embed(
    const int* __restrict__ tc, const int* __restrict__ tp, const int* __restrict__ td,
    const float* __restrict__ ec, const float* __restrict__ ep, const float* __restrict__ ed,
    const float* __restrict__ wv, const float* __restrict__ av,
    const float* __restrict__ iw, const float* __restrict__ ib,
    u16* __restrict__ ce_hi, u16* __restrict__ ce_lo,
    u16* __restrict__ vx_hi, u16* __restrict__ vx_lo) {
  int n = blockIdx.x, d = threadIdx.x;
  float a0 = 0.f, a1 = 0.f, a2 = 0.f;
#pragma unroll 4
  for (int l = 0; l < L_; l++) {
    a0 += ec[(size_t)tc[n * L_ + l] * D_ + d];
    a1 += ep[(size_t)tp[n * L_ + l] * D_ + d];
    a2 += ed[(size_t)td[n * L_ + l] * D_ + d];
  }
  size_t o0 = (size_t)n * D_ + d;
  u16 h;
  h = f2bf(a0); ce_hi[o0] = h;              ce_lo[o0] = f2bf(a0 - bf2f(h));
  h = f2bf(a1); ce_hi[(size_t)N_ * D_ + o0] = h; ce_lo[(size_t)N_ * D_ + o0] = f2bf(a1 - bf2f(h));
  h = f2bf(a2); ce_hi[(size_t)2 * N_ * D_ + o0] = h; ce_lo[(size_t)2 * N_ * D_ + o0] = f2bf(a2 - bf2f(h));
  float w = wv[n], a = av[n];
  float v1 = w * iw[d] + ib[d];
  float v2 = a * iw[D_ + d] + ib[D_ + d];
  h = f2bf(v1); vx_hi[(size_t)5 * N_ * D_ + o0] = h; vx_lo[(size_t)5 * N_ * D_ + o0] = f2bf(v1 - bf2f(h));
  h = f2bf(v2); vx_hi[(size_t)6 * N_ * D_ + o0] = h; vx_lo[(size_t)6 * N_ * D_ + o0] = f2bf(v2 - bf2f(h));
}

// ---------------- Kernel 2: monitor pair embeddings (lab / inj) ----------------
__global__ __launch_bounds__(128) void k_pair_embed(
    const int* __restrict__ tli, const int* __restrict__ tlv,
    const int* __restrict__ tii, const int* __restrict__ tiv,
    const float* __restrict__ eli, const float* __restrict__ elv,
    const float* __restrict__ eii, const float* __restrict__ eiv,
    u16* __restrict__ mx_hi, u16* __restrict__ mx_lo) {
  int r = blockIdx.x, d = threadIdx.x;
  float al = 0.f, ai = 0.f;
#pragma unroll 4
  for (int l = 0; l < L_; l++) {
    al += eli[(size_t)tli[r * L_ + l] * D_ + d] * elv[(size_t)tlv[r * L_ + l] * D_ + d];
    ai += eii[(size_t)tii[r * L_ + l] * D_ + d] * eiv[(size_t)tiv[r * L_ + l] * D_ + d];
  }
  size_t o = (size_t)r * D_ + d;
  u16 h;
  h = f2bf(al); mx_hi[o] = h;                      mx_lo[o] = f2bf(al - bf2f(h));
  h = f2bf(ai); mx_hi[(size_t)NM_ * D_ + o] = h;   mx_lo[(size_t)NM_ * D_ + o] = f2bf(ai - bf2f(h));
}

// ---------------- Kernel 3: xg = A @ W^T + bias, MFMA, hi/lo A and W ----------------
__global__ __launch_bounds__(256) void k_gemm_xg(
    const u16* __restrict__ A_hi, const u16* __restrict__ A_lo,
    const u16* __restrict__ W_hi, const u16* __restrict__ W_lo,
    const float* __restrict__ bias,
    float* __restrict__ out, int A_ks, int W_ks, int b_ks, int o_ks) {
  int key = blockIdx.z;
  int wv = threadIdx.x >> 6, lane = threadIdx.x & 63;
  int mn = lane & 15, q = lane >> 4;
  int row0 = blockIdx.x * 16;
  int col0 = blockIdx.y * 64 + wv * 16;
  const u16* Ah = A_hi + (size_t)key * A_ks + (size_t)(row0 + mn) * D_;
  const u16* Al = A_lo + (size_t)key * A_ks + (size_t)(row0 + mn) * D_;
  const u16* Wh = W_hi + (size_t)key * W_ks + (size_t)(col0 + mn) * D_;
  const u16* Wl = W_lo + (size_t)key * W_ks + (size_t)(col0 + mn) * D_;
  floatx4 acc0 = {0.f, 0.f, 0.f, 0.f};
  floatx4 acc1 = {0.f, 0.f, 0.f, 0.f};
  floatx4 acc2 = {0.f, 0.f, 0.f, 0.f};
#pragma unroll
  for (int kk = 0; kk < 4; kk++) {
    int off = kk * 32 + q * 8;
    bf16x8 a_h = *(const bf16x8*)(Ah + off);
    bf16x8 a_l = *(const bf16x8*)(Al + off);
    bf16x8 w_h = *(const bf16x8*)(Wh + off);
    bf16x8 w_l = *(const bf16x8*)(Wl + off);
    acc0 = mfma16(a_h, w_h, acc0);
    acc1 = mfma16(a_l, w_h, acc1);
    acc2 = mfma16(a_h, w_l, acc2);
  }
  int c = col0 + mn;
  float bv = bias[key * b_ks + c];
  float* op = out + (size_t)key * o_ks + (size_t)(row0 + q * 4) * G_ + c;
#pragma unroll
  for (int i = 0; i < 4; i++) op[(size_t)i * G_] = acc0[i] + acc1[i] + acc2[i] + bv;
}

// ---------------- Kernel 4: GRU recurrence (templated, fully unrolled T) ----------------
// MODE 0: monitor keys 0..4 (cpk chunks of 16 seqs); keys<3 t-const xg_a, keys>=3 xg_b.
// MODE 1: visit keys (cpk=1), xg_a rows b*16+t, f32 out.
// h state: separate hi/lo bf16 LDS planes in MFMA-fragment order, 16B-unit XOR swizzle,
// ping-pong parity; written with ds_write_b16, read with ds_read_b128 (no perms).
// xg: depth-2 register prefetch over 3 statically-renamed streams (full unroll).
template <int MODE, int TT>
__global__ __launch_bounds__(256, 1) void k_gru_t(
    int cpk, const float* __restrict__ xg_a, const float* __restrict__ xg_b,
    const u16* __restrict__ whh_all, const float* __restrict__ bhh_all,
    u16* __restrict__ out_hi, u16* __restrict__ out_lo, float* __restrict__ out_f32) {
  int key = blockIdx.x / cpk;
  int chunk = blockIdx.x % cpk;
  int n0 = chunk * 16;
  const u16* whh = whh_all + (size_t)key * (G_ * D_);
  const float* bhh = bhh_all + (size_t)key * G_;

  __shared__ u16 hls[2][2][16 * 128];

  int tid = threadIdx.x;
  int w = tid >> 6, lane = tid & 63, mq = lane & 15, q = lane >> 4;
  int dA = 16 * w + mq;

  // B fragments: tile j at col 16w + 64j (j = gate*2 + dgroup)
  bf16x8 bw[6][4];
#pragma unroll
  for (int j = 0; j < 6; j++)
#pragma unroll
    for (int kk = 0; kk < 4; kk++)
      bw[j][kk] = *(const bf16x8*)(whh + (size_t)(16 * w + 64 * j + mq) * D_ + kk * 32 + q * 8);

  float bias_g[6];
#pragma unroll
  for (int g = 0; g < 3; g++)
#pragma unroll
    for (int ab = 0; ab < 2; ab++) bias_g[g * 2 + ab] = bhh[g * 128 + ab * 64 + dA];

  const float* xbase;
  size_t RS, TS;
  if (MODE == 0) {
    if (key < 3) { xbase = xg_a + ((size_t)key * N_ + n0) * G_; RS = G_; TS = 0; }
    else { xbase = xg_b + ((size_t)(key - 3) * NM_ + (size_t)n0 * M_) * G_; RS = (size_t)M_ * G_; TS = G_; }
  } else {
    xbase = xg_a + (size_t)key * N_ * G_; RS = (size_t)16 * G_; TS = G_;
  }
  const float* rowp[4];
#pragma unroll
  for (int i = 0; i < 4; i++) rowp[i] = xbase + (size_t)(q * 4 + i) * RS + dA;

  // 3 statically-renamed xg streams (full unroll -> no rotation movs)
  float xb[3][24];
#pragma unroll
  for (int i = 0; i < 4; i++)
#pragma unroll
    for (int g = 0; g < 3; g++)
#pragma unroll
      for (int ab = 0; ab < 2; ab++) {
        xb[0][i * 6 + g * 2 + ab] = rowp[i][g * 128 + ab * 64];
        xb[1][i * 6 + g * 2 + ab] = rowp[i][TS + g * 128 + ab * 64];
      }

  float h_old[8];
#pragma unroll
  for (int k = 0; k < 8; k++) h_old[k] = 0.f;

#pragma unroll
  for (int t = 0; t < TT; t++) {
    if (t + 2 < TT) {
      size_t to = (size_t)(t + 2) * TS;
#pragma unroll
      for (int i = 0; i < 4; i++)
#pragma unroll
        for (int g = 0; g < 3; g++)
#pragma unroll
          for (int ab = 0; ab < 2; ab++)
            xb[(t + 2) % 3][i * 6 + g * 2 + ab] = rowp[i][to + g * 128 + ab * 64];
    }

    floatx4 acc_h[6], acc_l[6];
#pragma unroll
    for (int j = 0; j < 6; j++) {
      float bj = bias_g[j];
      acc_h[j] = {bj, bj, bj, bj};
      acc_l[j] = {0.f, 0.f, 0.f, 0.f};
    }

    if (t > 0) {
      const u16* hp0 = &hls[(t - 1) & 1][0][0];
      const u16* hp1 = &hls[(t - 1) & 1][1][0];
#pragma unroll
      for (int kk = 0; kk < 4; kk++) {
        int off = mq * 128 + (((kk * 4 + q) ^ mq) * 8);
        bf16x8 ah = *(const bf16x8*)(hp0 + off);
        bf16x8 al = *(const bf16x8*)(hp1 + off);
#pragma unroll
        for (int j = 0; j < 6; j++) {
          acc_h[j] = mfma16(ah, bw[j][kk], acc_h[j]);
          acc_l[j] = mfma16(al, bw[j][kk], acc_l[j]);
        }
      }
    }

    // gate phase — in-register
    const float* xcur = xb[t % 3];
    u16* wh = &hls[t & 1][0][0];
    u16* wl = &hls[t & 1][1][0];
#pragma unroll
    for (int i = 0; i < 4; i++) {
      int row = q * 4 + i;
#pragma unroll
      for (int ab = 0; ab < 2; ab++) {
        float ghr = acc_h[0 + ab][i] + acc_l[0 + ab][i];
        float ghz = acc_h[2 + ab][i] + acc_l[2 + ab][i];
        float ghn = acc_h[4 + ab][i] + acc_l[4 + ab][i];
        float xr = xcur[i * 6 + 0 + ab], xz = xcur[i * 6 + 2 + ab], xnn = xcur[i * 6 + 4 + ab];
        float r = sigm_(xr + ghr);
        float z = sigm_(xz + ghz);
        float nn = tanh_(xnn + r * ghn);
        float h2 = (1.0f - z) * nn + z * h_old[i * 2 + ab];
        h_old[i * 2 + ab] = h2;
        // truncation hi-split: lo absorbs the truncation error
        u32 ub = __builtin_bit_cast(u32, h2);
        u16 hb = (u16)(ub >> 16);
        float rem = h2 - __builtin_bit_cast(float, ub & 0xFFFF0000u);
        u16 lb = f2bf(rem);
        int d = dA + ab * 64;
        if (t == TT - 1) {
          if (MODE == 0) {
            size_t o = ((size_t)key * N_ + n0 + row) * D_ + d;
            out_hi[o] = hb;
            out_lo[o] = lb;
          } else {
            out_f32[((size_t)key * 16 + row) * D_ + d] = h2;
          }
        } else {
          int idx = row * 128 + (((d >> 3) ^ row) * 8) + (d & 7);
          wh[idx] = hb;
          wl[idx] = lb;
        }
      }
    }
    if (t + 1 < TT) lds_barrier();
  }
}

// ---------------- Kernel 5: ReLU + FC (parallel GEMV) ----------------
// grid (B_, 13); block 256 = 16 segs x 16 cols; 896-deep reduction split 16 ways.
__global__ __launch_bounds__(256) void k_fc(
    const float* __restrict__ vis_h, const float* __restrict__ fc_w,
    const float* __restrict__ fc_b, float* __restrict__ out) {
  int b = blockIdx.x;
  int cg = blockIdx.y;
  int tid = threadIdx.x;
  int j = tid & 15, s = tid >> 4;
  int c = cg * 16 + j;
  bool cv = c < OUT_;

  __shared__ float hbuf[7 * D_];
  __shared__ float red[16][16];
  for (int i = tid; i < 7 * D_; i += 256) {
    float v = vis_h[((size_t)(i >> 7) * 16 + b) * D_ + (i & 127)];
    hbuf[i] = v > 0.f ? v : 0.f;
  }
  __syncthreads();

  float acc = 0.f;
  if (cv) {
    const float* wp = fc_w + (size_t)(s * 56) * OUT_ + c;
#pragma unroll 8
    for (int k = 0; k < 56; k++) acc += hbuf[s * 56 + k] * wp[(size_t)k * OUT_];
  }
  red[s][j] = acc;
  __syncthreads();
  if (s == 0 && cv) {
    float t = 0.f;
#pragma unroll
    for (int m = 0; m < 16; m++) t += red[m][j];
    out[(size_t)b * OUT_ + c] = t + fc_b[c];
  }
}

extern "C" void kernel_launch(void* const* d_in, const int* in_sizes, int n_in,
                              void* d_out, int out_size, void* d_ws, size_t ws_size,
                              hipStream_t stream) {
  (void)in_sizes; (void)n_in; (void)out_size; (void)ws_size;
  const int* tok_cond = (const int*)d_in[0];
  const int* tok_proc = (const int*)d_in[1];
  const int* tok_drug = (const int*)d_in[2];
  const int* tok_lab_item = (const int*)d_in[3];
  const int* tok_lab_value = (const int*)d_in[4];
  const int* tok_inj_item = (const int*)d_in[5];
  const int* tok_inj_value = (const int*)d_in[6];
  const float* weight = (const float*)d_in[7];
  const float* age = (const float*)d_in[8];
  const float* emb_cond = (const float*)d_in[9];
  const float* emb_proc = (const float*)d_in[10];
  const float* emb_drug = (const float*)d_in[11];
  const float* emb_lab_item = (const float*)d_in[12];
  const float* emb_lab_value = (const float*)d_in[13];
  const float* emb_inj_item = (const float*)d_in[14];
  const float* emb_inj_value = (const float*)d_in[15];
  const float* mgru_wih = (const float*)d_in[16];
  const float* mgru_whh = (const float*)d_in[17];
  const float* mgru_bih = (const float*)d_in[18];
  const float* mgru_bhh = (const float*)d_in[19];
  const float* vgru_wih = (const float*)d_in[20];
  const float* vgru_whh = (const float*)d_in[21];
  const float* vgru_bih = (const float*)d_in[22];
  const float* vgru_bhh = (const float*)d_in[23];
  const float* info_w = (const float*)d_in[24];
  const float* info_b = (const float*)d_in[25];
  const float* fc_w = (const float*)d_in[26];
  const float* fc_b = (const float*)d_in[27];

  char* p = (char*)d_ws;
  auto take = [&](size_t bytes) { char* r = p; p += (bytes + 255) & ~(size_t)255; return r; };
  u16* mon_x_hi = (u16*)take((size_t)2 * NM_ * D_ * 2);
  u16* mon_x_lo = (u16*)take((size_t)2 * NM_ * D_ * 2);
  u16* ce_hi = (u16*)take((size_t)3 * N_ * D_ * 2);
  u16* ce_lo = (u16*)take((size_t)3 * N_ * D_ * 2);
  u16* vis_x_hi = (u16*)take((size_t)7 * N_ * D_ * 2);
  u16* vis_x_lo = (u16*)take((size_t)7 * N_ * D_ * 2);
  float* xg_mon = (float*)take((size_t)2 * NM_ * G_ * 4);
  float* xg_c = (float*)take((size_t)3 * N_ * G_ * 4);
  float* xg_v = (float*)take((size_t)7 * N_ * G_ * 4);
  float* vis_h = (float*)take((size_t)7 * 16 * D_ * 4);
  u16* wih_hi = (u16*)take((size_t)12 * G_ * D_ * 2);
  u16* wih_lo = (u16*)take((size_t)12 * G_ * D_ * 2);
  u16* whh_hi = (u16*)take((size_t)12 * G_ * D_ * 2);
  u16* whh_lo = (u16*)take((size_t)12 * G_ * D_ * 2);

  k_conv_w<<<(24 * G_ * D_) / 256, 256, 0, stream>>>(mgru_wih, vgru_wih, mgru_whh, vgru_whh,
                                                     wih_hi, wih_lo, whh_hi, whh_lo);
  k_visit_embed<<<N_, D_, 0, stream>>>(tok_cond, tok_proc, tok_drug, emb_cond, emb_proc, emb_drug,
                                       weight, age, info_w, info_b, ce_hi, ce_lo, vis_x_hi, vis_x_lo);
  k_pair_embed<<<NM_, D_, 0, stream>>>(tok_lab_item, tok_lab_value, tok_inj_item, tok_inj_value,
                                       emb_lab_item, emb_lab_value, emb_inj_item, emb_inj_value,
                                       mon_x_hi, mon_x_lo);
  k_gemm_xg<<<dim3(NM_ / 16, 6, 2), 256, 0, stream>>>(
      mon_x_hi, mon_x_lo, wih_hi + (size_t)3 * G_ * D_, wih_lo + (size_t)3 * G_ * D_,
      mgru_bih + 3 * G_, xg_mon, NM_ * D_, G_ * D_, G_, NM_ * G_);
  k_gemm_xg<<<dim3(N_ / 16, 6, 3), 256, 0, stream>>>(
      ce_hi, ce_lo, wih_hi, wih_lo, mgru_bih, xg_c, N_ * D_, G_ * D_, G_, N_ * G_);
  k_gru_t<0, 32><<<80, 256, 0, stream>>>(16, xg_c, xg_mon, whh_hi, mgru_bhh,
                                         vis_x_hi, vis_x_lo, nullptr);
  k_gemm_xg<<<dim3(N_ / 16, 6, 7), 256, 0, stream>>>(
      vis_x_hi, vis_x_lo, wih_hi + (size_t)5 * G_ * D_, wih_lo + (size_t)5 * G_ * D_,
      vgru_bih, xg_v, N_ * D_, G_ * D_, G_, N_ * G_);
  k_gru_t<1, 16><<<7, 256, 0, stream>>>(1, xg_v, nullptr, whh_hi + (size_t)5 * G_ * D_, vgru_bhh,
                                        nullptr, nullptr, vis_h);
  k_fc<<<dim3(B_, 13), 256, 0, stream>>>(vis_h, fc_w, fc_b, (float*)d_out);
}

// Round 7
// 264.759 us; speedup vs baseline: 1.2646x; 1.1187x over previous
//
#include <hip/hip_runtime.h>
#include <stdint.h>

typedef unsigned short u16;
typedef unsigned int u32;

#define B_ 16
#define V_ 16
#define M_ 32
#define L_ 24
#define D_ 128
#define G_ 384   // 3*D
#define N_ 256   // B*V
#define NM_ 8192 // B*V*M
#define OUT_ 193

using bf16x8 = __attribute__((ext_vector_type(8))) __bf16;
using floatx4 = __attribute__((ext_vector_type(4))) float;

__device__ __forceinline__ float bf2f(u16 u) {
  u32 x = ((u32)u) << 16;
  return __builtin_bit_cast(float, x);
}
__device__ __forceinline__ u16 f2bf(float f) {
  u32 u = __builtin_bit_cast(u32, f);
  u = (u + 0x7FFFu + ((u >> 16) & 1u)) >> 16;
  return (u16)u;
}
__device__ __forceinline__ float sigm_(float x) {
  return __builtin_amdgcn_rcpf(1.0f + __expf(-x));
}
__device__ __forceinline__ float tanh_(float x) {
  float e = __expf(2.0f * x);
  return 1.0f - 2.0f * __builtin_amdgcn_rcpf(e + 1.0f);
}
__device__ __forceinline__ floatx4 mfma16(bf16x8 a, bf16x8 b, floatx4 c) {
  return __builtin_amdgcn_mfma_f32_16x16x32_bf16(a, b, c, 0, 0, 0);
}
// LDS-only barrier: drains lgkmcnt but leaves global loads (vmcnt) in flight.
__device__ __forceinline__ void lds_barrier() {
  asm volatile("s_waitcnt lgkmcnt(0)\n\ts_barrier" ::: "memory");
}

// ---------------- Kernel 0: convert f32 GRU weights -> hi/lo bf16 planes ----------------
__global__ __launch_bounds__(256) void k_conv_w(
    const float* __restrict__ mwih, const float* __restrict__ vwih,
    const float* __restrict__ mwhh, const float* __restrict__ vwhh,
    u16* __restrict__ wih_hi, u16* __restrict__ wih_lo,
    u16* __restrict__ whh_hi, u16* __restrict__ whh_lo) {
  const int S5 = 5 * G_ * D_, S12 = 12 * G_ * D_;
  int i = blockIdx.x * 256 + threadIdx.x;
  float v;
  u16 *dh, *dl;
  int o;
  if (i < S12) {
    o = i;
    v = (o < S5) ? mwih[o] : vwih[o - S5];
    dh = wih_hi; dl = wih_lo;
  } else {
    o = i - S12;
    v = (o < S5) ? mwhh[o] : vwhh[o - S5];
    dh = whh_hi; dl = whh_lo;
  }
  u16 h = f2bf(v);
  dh[o] = h;
  dl[o] = f2bf(v - bf2f(h));
}

// ---------------- Kernel 1: visit-event embeddings + info linears ----------------
__global__ __launch_bounds__(128) void k_visit_embed(
    const int* __restrict__ tc, const int* __restrict__ tp, const int* __restrict__ td,
    const float* __restrict__ ec, const float* __restrict__ ep, const float* __restrict__ ed,
    const float* __restrict__ wv, const float* __restrict__ av,
    const float* __restrict__ iw, const float* __restrict__ ib,
    u16* __restrict__ ce_hi, u16* __restrict__ ce_lo,
    u16* __restrict__ vx_hi, u16* __restrict__ vx_lo) {
  int n = blockIdx.x, d = threadIdx.x;
  float a0 = 0.f, a1 = 0.f, a2 = 0.f;
#pragma unroll 4
  for (int l = 0; l < L_; l++) {
    a0 += ec[(size_t)tc[n * L_ + l] * D_ + d];
    a1 += ep[(size_t)tp[n * L_ + l] * D_ + d];
    a2 += ed[(size_t)td[n * L_ + l] * D_ + d];
  }
  size_t o0 = (size_t)n * D_ + d;
  u16 h;
  h = f2bf(a0); ce_hi[o0] = h;              ce_lo[o0] = f2bf(a0 - bf2f(h));
  h = f2bf(a1); ce_hi[(size_t)N_ * D_ + o0] = h; ce_lo[(size_t)N_ * D_ + o0] = f2bf(a1 - bf2f(h));
  h = f2bf(a2); ce_hi[(size_t)2 * N_ * D_ + o0] = h; ce_lo[(size_t)2 * N_ * D_ + o0] = f2bf(a2 - bf2f(h));
  float w = wv[n], a = av[n];
  float v1 = w * iw[d] + ib[d];
  float v2 = a * iw[D_ + d] + ib[D_ + d];
  h = f2bf(v1); vx_hi[(size_t)5 * N_ * D_ + o0] = h; vx_lo[(size_t)5 * N_ * D_ + o0] = f2bf(v1 - bf2f(h));
  h = f2bf(v2); vx_hi[(size_t)6 * N_ * D_ + o0] = h; vx_lo[(size_t)6 * N_ * D_ + o0] = f2bf(v2 - bf2f(h));
}

// ---------------- Kernel 2: monitor pair embeddings (lab / inj) ----------------
__global__ __launch_bounds__(128) void k_pair_embed(
    const int* __restrict__ tli, const int* __restrict__ tlv,
    const int* __restrict__ tii, const int* __restrict__ tiv,
    const float* __restrict__ eli, const float* __restrict__ elv,
    const float* __restrict__ eii, const float* __restrict__ eiv,
    u16* __restrict__ mx_hi, u16* __restrict__ mx_lo) {
  int r = blockIdx.x, d = threadIdx.x;
  float al = 0.f, ai = 0.f;
#pragma unroll 4
  for (int l = 0; l < L_; l++) {
    al += eli[(size_t)tli[r * L_ + l] * D_ + d] * elv[(size_t)tlv[r * L_ + l] * D_ + d];
    ai += eii[(size_t)tii[r * L_ + l] * D_ + d] * eiv[(size_t)tiv[r * L_ + l] * D_ + d];
  }
  size_t o = (size_t)r * D_ + d;
  u16 h;
  h = f2bf(al); mx_hi[o] = h;                      mx_lo[o] = f2bf(al - bf2f(h));
  h = f2bf(ai); mx_hi[(size_t)NM_ * D_ + o] = h;   mx_lo[(size_t)NM_ * D_ + o] = f2bf(ai - bf2f(h));
}

// ---------------- Kernel 3: xg = A @ W^T + bias, MFMA, hi/lo A and W ----------------
__global__ __launch_bounds__(256) void k_gemm_xg(
    const u16* __restrict__ A_hi, const u16* __restrict__ A_lo,
    const u16* __restrict__ W_hi, const u16* __restrict__ W_lo,
    const float* __restrict__ bias,
    float* __restrict__ out, int A_ks, int W_ks, int b_ks, int o_ks) {
  int key = blockIdx.z;
  int wv = threadIdx.x >> 6, lane = threadIdx.x & 63;
  int mn = lane & 15, q = lane >> 4;
  int row0 = blockIdx.x * 16;
  int col0 = blockIdx.y * 64 + wv * 16;
  const u16* Ah = A_hi + (size_t)key * A_ks + (size_t)(row0 + mn) * D_;
  const u16* Al = A_lo + (size_t)key * A_ks + (size_t)(row0 + mn) * D_;
  const u16* Wh = W_hi + (size_t)key * W_ks + (size_t)(col0 + mn) * D_;
  const u16* Wl = W_lo + (size_t)key * W_ks + (size_t)(col0 + mn) * D_;
  floatx4 acc0 = {0.f, 0.f, 0.f, 0.f};
  floatx4 acc1 = {0.f, 0.f, 0.f, 0.f};
  floatx4 acc2 = {0.f, 0.f, 0.f, 0.f};
#pragma unroll
  for (int kk = 0; kk < 4; kk++) {
    int off = kk * 32 + q * 8;
    bf16x8 a_h = *(const bf16x8*)(Ah + off);
    bf16x8 a_l = *(const bf16x8*)(Al + off);
    bf16x8 w_h = *(const bf16x8*)(Wh + off);
    bf16x8 w_l = *(const bf16x8*)(Wl + off);
    acc0 = mfma16(a_h, w_h, acc0);
    acc1 = mfma16(a_l, w_h, acc1);
    acc2 = mfma16(a_h, w_l, acc2);
  }
  int c = col0 + mn;
  float bv = bias[key * b_ks + c];
  float* op = out + (size_t)key * o_ks + (size_t)(row0 + q * 4) * G_ + c;
#pragma unroll
  for (int i = 0; i < 4; i++) op[(size_t)i * G_] = acc0[i] + acc1[i] + acc2[i] + bv;
}

// ---------------- Kernel 4: GRU recurrence (partial unroll x4, fused acc chains) ----------------
// 4 statically-indexed xg register streams -> prefetch distance 3 steps, no rotation movs,
// no full-unroll register blowup (R6 spilled: WRITE_SIZE 7 MB).
// One 8-deep MFMA chain per gate-tile j, seeded with bias splat as C of the first MFMA.
template <int MODE, int TT>
__global__ __launch_bounds__(256, 1) void k_gru_t(
    int cpk, const float* __restrict__ xg_a, const float* __restrict__ xg_b,
    const u16* __restrict__ whh_all, const float* __restrict__ bhh_all,
    u16* __restrict__ out_hi, u16* __restrict__ out_lo, float* __restrict__ out_f32) {
  int key = blockIdx.x / cpk;
  int chunk = blockIdx.x % cpk;
  int n0 = chunk * 16;
  const u16* whh = whh_all + (size_t)key * (G_ * D_);
  const float* bhh = bhh_all + (size_t)key * G_;

  __shared__ u16 hls[2][2][16 * 128];

  int tid = threadIdx.x;
  int w = tid >> 6, lane = tid & 63, mq = lane & 15, q = lane >> 4;
  int dA = 16 * w + mq;

  bf16x8 bw[6][4];
#pragma unroll
  for (int j = 0; j < 6; j++)
#pragma unroll
    for (int kk = 0; kk < 4; kk++)
      bw[j][kk] = *(const bf16x8*)(whh + (size_t)(16 * w + 64 * j + mq) * D_ + kk * 32 + q * 8);

  floatx4 bias_v[6];
#pragma unroll
  for (int g = 0; g < 3; g++)
#pragma unroll
    for (int ab = 0; ab < 2; ab++) {
      float b = bhh[g * 128 + ab * 64 + dA];
      bias_v[g * 2 + ab] = {b, b, b, b};
    }

  const float* xbase;
  size_t RS, TS;
  if (MODE == 0) {
    if (key < 3) { xbase = xg_a + ((size_t)key * N_ + n0) * G_; RS = G_; TS = 0; }
    else { xbase = xg_b + ((size_t)(key - 3) * NM_ + (size_t)n0 * M_) * G_; RS = (size_t)M_ * G_; TS = G_; }
  } else {
    xbase = xg_a + (size_t)key * N_ * G_; RS = (size_t)16 * G_; TS = G_;
  }
  const float* rowp[4];
#pragma unroll
  for (int i = 0; i < 4; i++) rowp[i] = xbase + (size_t)(q * 4 + i) * RS + dA;

  // 4 statically-indexed streams; stream P holds xg for time t with t%4==P.
  float xs[4][24];
#pragma unroll
  for (int s = 0; s < 3; s++) {
    int ts = s < TT ? s : TT - 1;
#pragma unroll
    for (int i = 0; i < 4; i++)
#pragma unroll
      for (int g = 0; g < 3; g++)
#pragma unroll
        for (int ab = 0; ab < 2; ab++)
          xs[s][i * 6 + g * 2 + ab] = rowp[i][(size_t)ts * TS + g * 128 + ab * 64];
  }

  float h_old[8];
#pragma unroll
  for (int k = 0; k < 8; k++) h_old[k] = 0.f;

#define GRU_STEP(P)                                                                        \
  {                                                                                        \
    int t = tb + (P);                                                                      \
    /* prefetch xg(t+3) into stream (P+3)&3 (time clamped; redundant at tail is fine) */   \
    {                                                                                      \
      int tpf = t + 3 < TT ? t + 3 : TT - 1;                                               \
      size_t to = (size_t)tpf * TS;                                                        \
      _Pragma("unroll") for (int i = 0; i < 4; i++)                                        \
          _Pragma("unroll") for (int g = 0; g < 3; g++)                                    \
          _Pragma("unroll") for (int ab = 0; ab < 2; ab++)                                 \
              xs[((P) + 3) & 3][i * 6 + g * 2 + ab] = rowp[i][to + g * 128 + ab * 64];     \
    }                                                                                      \
    floatx4 acc[6];                                                                        \
    if (t > 0) {                                                                           \
      const u16* hp0 = &hls[(t - 1) & 1][0][0];                                            \
      const u16* hp1 = &hls[(t - 1) & 1][1][0];                                            \
      bf16x8 ah[4], al[4];                                                                 \
      _Pragma("unroll") for (int kk = 0; kk < 4; kk++) {                                   \
        int off = mq * 128 + (((kk * 4 + q) ^ mq) * 8);                                    \
        ah[kk] = *(const bf16x8*)(hp0 + off);                                              \
        al[kk] = *(const bf16x8*)(hp1 + off);                                              \
      }                                                                                    \
      _Pragma("unroll") for (int j = 0; j < 6; j++) {                                      \
        floatx4 a = mfma16(ah[0], bw[j][0], bias_v[j]);                                    \
        a = mfma16(al[0], bw[j][0], a);                                                    \
        a = mfma16(ah[1], bw[j][1], a);                                                    \
        a = mfma16(al[1], bw[j][1], a);                                                    \
        a = mfma16(ah[2], bw[j][2], a);                                                    \
        a = mfma16(al[2], bw[j][2], a);                                                    \
        a = mfma16(ah[3], bw[j][3], a);                                                    \
        acc[j] = mfma16(al[3], bw[j][3], a);                                               \
      }                                                                                    \
    } else {                                                                               \
      _Pragma("unroll") for (int j = 0; j < 6; j++) acc[j] = bias_v[j];                    \
    }                                                                                      \
    u16* wrh = &hls[t & 1][0][0];                                                          \
    u16* wrl = &hls[t & 1][1][0];                                                          \
    _Pragma("unroll") for (int i = 0; i < 4; i++) {                                        \
      int row = q * 4 + i;                                                                 \
      _Pragma("unroll") for (int ab = 0; ab < 2; ab++) {                                   \
        float ghr = acc[0 + ab][i];                                                        \
        float ghz = acc[2 + ab][i];                                                        \
        float ghn = acc[4 + ab][i];                                                        \
        float xr = xs[P][i * 6 + 0 + ab];                                                  \
        float xz = xs[P][i * 6 + 2 + ab];                                                  \
        float xnn = xs[P][i * 6 + 4 + ab];                                                 \
        float r = sigm_(xr + ghr);                                                         \
        float z = sigm_(xz + ghz);                                                         \
        float nn = tanh_(xnn + r * ghn);                                                   \
        float h2 = (1.0f - z) * nn + z * h_old[i * 2 + ab];                                \
        h_old[i * 2 + ab] = h2;                                                            \
        u32 ub = __builtin_bit_cast(u32, h2);                                              \
        u16 hb = (u16)(ub >> 16);                                                          \
        float rem = h2 - __builtin_bit_cast(float, ub & 0xFFFF0000u);                      \
        u16 lb = f2bf(rem);                                                                \
        int d = dA + ab * 64;                                                              \
        if (t == TT - 1) {                                                                 \
          if (MODE == 0) {                                                                 \
            size_t o = ((size_t)key * N_ + n0 + row) * D_ + d;                             \
            out_hi[o] = hb;                                                                \
            out_lo[o] = lb;                                                                \
          } else {                                                                         \
            out_f32[((size_t)key * 16 + row) * D_ + d] = h2;                               \
          }                                                                                \
        } else {                                                                           \
          int idx = row * 128 + (((d >> 3) ^ row) * 8) + (d & 7);                          \
          wrh[idx] = hb;                                                                   \
          wrl[idx] = lb;                                                                   \
        }                                                                                  \
      }                                                                                    \
    }                                                                                      \
    if (t + 1 < TT) lds_barrier();                                                         \
  }

#pragma unroll 1
  for (int tb = 0; tb < TT; tb += 4) {
    GRU_STEP(0)
    GRU_STEP(1)
    GRU_STEP(2)
    GRU_STEP(3)
  }
#undef GRU_STEP
}

// ---------------- Kernel 5: ReLU + FC (parallel GEMV) ----------------
__global__ __launch_bounds__(256) void k_fc(
    const float* __restrict__ vis_h, const float* __restrict__ fc_w,
    const float* __restrict__ fc_b, float* __restrict__ out) {
  int b = blockIdx.x;
  int cg = blockIdx.y;
  int tid = threadIdx.x;
  int j = tid & 15, s = tid >> 4;
  int c = cg * 16 + j;
  bool cv = c < OUT_;

  __shared__ float hbuf[7 * D_];
  __shared__ float red[16][16];
  for (int i = tid; i < 7 * D_; i += 256) {
    float v = vis_h[((size_t)(i >> 7) * 16 + b) * D_ + (i & 127)];
    hbuf[i] = v > 0.f ? v : 0.f;
  }
  __syncthreads();

  float acc = 0.f;
  if (cv) {
    const float* wp = fc_w + (size_t)(s * 56) * OUT_ + c;
#pragma unroll 8
    for (int k = 0; k < 56; k++) acc += hbuf[s * 56 + k] * wp[(size_t)k * OUT_];
  }
  red[s][j] = acc;
  __syncthreads();
  if (s == 0 && cv) {
    float t = 0.f;
#pragma unroll
    for (int m = 0; m < 16; m++) t += red[m][j];
    out[(size_t)b * OUT_ + c] = t + fc_b[c];
  }
}

extern "C" void kernel_launch(void* const* d_in, const int* in_sizes, int n_in,
                              void* d_out, int out_size, void* d_ws, size_t ws_size,
                              hipStream_t stream) {
  (void)in_sizes; (void)n_in; (void)out_size; (void)ws_size;
  const int* tok_cond = (const int*)d_in[0];
  const int* tok_proc = (const int*)d_in[1];
  const int* tok_drug = (const int*)d_in[2];
  const int* tok_lab_item = (const int*)d_in[3];
  const int* tok_lab_value = (const int*)d_in[4];
  const int* tok_inj_item = (const int*)d_in[5];
  const int* tok_inj_value = (const int*)d_in[6];
  const float* weight = (const float*)d_in[7];
  const float* age = (const float*)d_in[8];
  const float* emb_cond = (const float*)d_in[9];
  const float* emb_proc = (const float*)d_in[10];
  const float* emb_drug = (const float*)d_in[11];
  const float* emb_lab_item = (const float*)d_in[12];
  const float* emb_lab_value = (const float*)d_in[13];
  const float* emb_inj_item = (const float*)d_in[14];
  const float* emb_inj_value = (const float*)d_in[15];
  const float* mgru_wih = (const float*)d_in[16];
  const float* mgru_whh = (const float*)d_in[17];
  const float* mgru_bih = (const float*)d_in[18];
  const float* mgru_bhh = (const float*)d_in[19];
  const float* vgru_wih = (const float*)d_in[20];
  const float* vgru_whh = (const float*)d_in[21];
  const float* vgru_bih = (const float*)d_in[22];
  const float* vgru_bhh = (const float*)d_in[23];
  const float* info_w = (const float*)d_in[24];
  const float* info_b = (const float*)d_in[25];
  const float* fc_w = (const float*)d_in[26];
  const float* fc_b = (const float*)d_in[27];

  char* p = (char*)d_ws;
  auto take = [&](size_t bytes) { char* r = p; p += (bytes + 255) & ~(size_t)255; return r; };
  u16* mon_x_hi = (u16*)take((size_t)2 * NM_ * D_ * 2);
  u16* mon_x_lo = (u16*)take((size_t)2 * NM_ * D_ * 2);
  u16* ce_hi = (u16*)take((size_t)3 * N_ * D_ * 2);
  u16* ce_lo = (u16*)take((size_t)3 * N_ * D_ * 2);
  u16* vis_x_hi = (u16*)take((size_t)7 * N_ * D_ * 2);
  u16* vis_x_lo = (u16*)take((size_t)7 * N_ * D_ * 2);
  float* xg_mon = (float*)take((size_t)2 * NM_ * G_ * 4);
  float* xg_c = (float*)take((size_t)3 * N_ * G_ * 4);
  float* xg_v = (float*)take((size_t)7 * N_ * G_ * 4);
  float* vis_h = (float*)take((size_t)7 * 16 * D_ * 4);
  u16* wih_hi = (u16*)take((size_t)12 * G_ * D_ * 2);
  u16* wih_lo = (u16*)take((size_t)12 * G_ * D_ * 2);
  u16* whh_hi = (u16*)take((size_t)12 * G_ * D_ * 2);
  u16* whh_lo = (u16*)take((size_t)12 * G_ * D_ * 2);

  k_conv_w<<<(24 * G_ * D_) / 256, 256, 0, stream>>>(mgru_wih, vgru_wih, mgru_whh, vgru_whh,
                                                     wih_hi, wih_lo, whh_hi, whh_lo);
  k_visit_embed<<<N_, D_, 0, stream>>>(tok_cond, tok_proc, tok_drug, emb_cond, emb_proc, emb_drug,
                                       weight, age, info_w, info_b, ce_hi, ce_lo, vis_x_hi, vis_x_lo);
  k_pair_embed<<<NM_, D_, 0, stream>>>(tok_lab_item, tok_lab_value, tok_inj_item, tok_inj_value,
                                       emb_lab_item, emb_lab_value, emb_inj_item, emb_inj_value,
                                       mon_x_hi, mon_x_lo);
  k_gemm_xg<<<dim3(NM_ / 16, 6, 2), 256, 0, stream>>>(
      mon_x_hi, mon_x_lo, wih_hi + (size_t)3 * G_ * D_, wih_lo + (size_t)3 * G_ * D_,
      mgru_bih + 3 * G_, xg_mon, NM_ * D_, G_ * D_, G_, NM_ * G_);
  k_gemm_xg<<<dim3(N_ / 16, 6, 3), 256, 0, stream>>>(
      ce_hi, ce_lo, wih_hi, wih_lo, mgru_bih, xg_c, N_ * D_, G_ * D_, G_, N_ * G_);
  k_gru_t<0, 32><<<80, 256, 0, stream>>>(16, xg_c, xg_mon, whh_hi, mgru_bhh,
                                         vis_x_hi, vis_x_lo, nullptr);
  k_gemm_xg<<<dim3(N_ / 16, 6, 7), 256, 0, stream>>>(
      vis_x_hi, vis_x_lo, wih_hi + (size_t)5 * G_ * D_, wih_lo + (size_t)5 * G_ * D_,
      vgru_bih, xg_v, N_ * D_, G_ * D_, G_, N_ * G_);
  k_gru_t<1, 16><<<7, 256, 0, stream>>>(1, xg_v, nullptr, whh_hi + (size_t)5 * G_ * D_, vgru_bhh,
                                        nullptr, nullptr, vis_h);
  k_fc<<<dim3(B_, 13), 256, 0, stream>>>(vis_h, fc_w, fc_b, (float*)d_out);
}

// Round 8
// 235.345 us; speedup vs baseline: 1.4227x; 1.1250x over previous
//
#include <hip/hip_runtime.h>
#include <stdint.h>

typedef unsigned short u16;
typedef unsigned int u32;

#define B_ 16
#define V_ 16
#define M_ 32
#define L_ 24
#define D_ 128
#define G_ 384   // 3*D
#define N_ 256   // B*V
#define NM_ 8192 // B*V*M
#define OUT_ 193

using bf16x8 = __attribute__((ext_vector_type(8))) __bf16;
using floatx4 = __attribute__((ext_vector_type(4))) float;

__device__ __forceinline__ float bf2f(u16 u) {
  u32 x = ((u32)u) << 16;
  return __builtin_bit_cast(float, x);
}
__device__ __forceinline__ u16 f2bf(float f) {
  u32 u = __builtin_bit_cast(u32, f);
  u = (u + 0x7FFFu + ((u >> 16) & 1u)) >> 16;
  return (u16)u;
}
__device__ __forceinline__ float sigm_(float x) {
  return __builtin_amdgcn_rcpf(1.0f + __expf(-x));
}
__device__ __forceinline__ float tanh_(float x) {
  float e = __expf(2.0f * x);
  return 1.0f - 2.0f * __builtin_amdgcn_rcpf(e + 1.0f);
}
__device__ __forceinline__ floatx4 mfma16(bf16x8 a, bf16x8 b, floatx4 c) {
  return __builtin_amdgcn_mfma_f32_16x16x32_bf16(a, b, c, 0, 0, 0);
}
// LDS-only barrier: drains lgkmcnt but leaves global loads (vmcnt) in flight.
__device__ __forceinline__ void lds_barrier() {
  asm volatile("s_waitcnt lgkmcnt(0)\n\ts_barrier" ::: "memory");
}

// ---------------- Kernel 0: convert f32 GRU weights -> hi/lo bf16 planes ----------------
__global__ __launch_bounds__(256) void k_conv_w(
    const float* __restrict__ mwih, const float* __restrict__ vwih,
    const float* __restrict__ mwhh, const float* __restrict__ vwhh,
    u16* __restrict__ wih_hi, u16* __restrict__ wih_lo,
    u16* __restrict__ whh_hi, u16* __restrict__ whh_lo) {
  const int S5 = 5 * G_ * D_, S12 = 12 * G_ * D_;
  int i = blockIdx.x * 256 + threadIdx.x;
  float v;
  u16 *dh, *dl;
  int o;
  if (i < S12) {
    o = i;
    v = (o < S5) ? mwih[o] : vwih[o - S5];
    dh = wih_hi; dl = wih_lo;
  } else {
    o = i - S12;
    v = (o < S5) ? mwhh[o] : vwhh[o - S5];
    dh = whh_hi; dl = whh_lo;
  }
  u16 h = f2bf(v);
  dh[o] = h;
  dl[o] = f2bf(v - bf2f(h));
}

// ---------------- Kernel 1: visit-event embeddings + info linears ----------------
__global__ __launch_bounds__(128) void k_visit_embed(
    const int* __restrict__ tc, const int* __restrict__ tp, const int* __restrict__ td,
    const float* __restrict__ ec, const float* __restrict__ ep, const float* __restrict__ ed,
    const float* __restrict__ wv, const float* __restrict__ av,
    const float* __restrict__ iw, const float* __restrict__ ib,
    u16* __restrict__ ce_hi, u16* __restrict__ ce_lo,
    u16* __restrict__ vx_hi, u16* __restrict__ vx_lo) {
  int n = blockIdx.x, d = threadIdx.x;
  float a0 = 0.f, a1 = 0.f, a2 = 0.f;
#pragma unroll 4
  for (int l = 0; l < L_; l++) {
    a0 += ec[(size_t)tc[n * L_ + l] * D_ + d];
    a1 += ep[(size_t)tp[n * L_ + l] * D_ + d];
    a2 += ed[(size_t)td[n * L_ + l] * D_ + d];
  }
  size_t o0 = (size_t)n * D_ + d;
  u16 h;
  h = f2bf(a0); ce_hi[o0] = h;              ce_lo[o0] = f2bf(a0 - bf2f(h));
  h = f2bf(a1); ce_hi[(size_t)N_ * D_ + o0] = h; ce_lo[(size_t)N_ * D_ + o0] = f2bf(a1 - bf2f(h));
  h = f2bf(a2); ce_hi[(size_t)2 * N_ * D_ + o0] = h; ce_lo[(size_t)2 * N_ * D_ + o0] = f2bf(a2 - bf2f(h));
  float w = wv[n], a = av[n];
  float v1 = w * iw[d] + ib[d];
  float v2 = a * iw[D_ + d] + ib[D_ + d];
  h = f2bf(v1); vx_hi[(size_t)5 * N_ * D_ + o0] = h; vx_lo[(size_t)5 * N_ * D_ + o0] = f2bf(v1 - bf2f(h));
  h = f2bf(v2); vx_hi[(size_t)6 * N_ * D_ + o0] = h; vx_lo[(size_t)6 * N_ * D_ + o0] = f2bf(v2 - bf2f(h));
}

// ---------------- Kernel 2: monitor pair embeddings (lab / inj) ----------------
__global__ __launch_bounds__(128) void k_pair_embed(
    const int* __restrict__ tli, const int* __restrict__ tlv,
    const int* __restrict__ tii, const int* __restrict__ tiv,
    const float* __restrict__ eli, const float* __restrict__ elv,
    const float* __restrict__ eii, const float* __restrict__ eiv,
    u16* __restrict__ mx_hi, u16* __restrict__ mx_lo) {
  int r = blockIdx.x, d = threadIdx.x;
  float al = 0.f, ai = 0.f;
#pragma unroll 4
  for (int l = 0; l < L_; l++) {
    al += eli[(size_t)tli[r * L_ + l] * D_ + d] * elv[(size_t)tlv[r * L_ + l] * D_ + d];
    ai += eii[(size_t)tii[r * L_ + l] * D_ + d] * eiv[(size_t)tiv[r * L_ + l] * D_ + d];
  }
  size_t o = (size_t)r * D_ + d;
  u16 h;
  h = f2bf(al); mx_hi[o] = h;                      mx_lo[o] = f2bf(al - bf2f(h));
  h = f2bf(ai); mx_hi[(size_t)NM_ * D_ + o] = h;   mx_lo[(size_t)NM_ * D_ + o] = f2bf(ai - bf2f(h));
}

// ---------------- Kernel 3: xg = A @ W^T + bias (tiled: wave = 16 rows x 96 cols) ----------------
// W hi-plane fragments held in registers (6 col-tiles), A hi/lo loaded once and reused
// across all 6 tiles. Bias splat seeds the MFMA chain's C operand.
// grid (rows/64, 4, nkeys), block 256 (wave w = row group w).
__global__ __launch_bounds__(256) void k_gemm_xg(
    const u16* __restrict__ A_hi, const u16* __restrict__ A_lo,
    const u16* __restrict__ W_hi,
    const float* __restrict__ bias,
    float* __restrict__ out, int A_ks, int W_ks, int b_ks, int o_ks) {
  int key = blockIdx.z;
  int w = threadIdx.x >> 6, lane = threadIdx.x & 63;
  int mq = lane & 15, q = lane >> 4;
  int row = blockIdx.x * 64 + w * 16;
  int cb = blockIdx.y * 96;

  // W fragments: 6 col-tiles x 4 k-chunks (hi plane only; lo-W term ~1e-4, below budget)
  const u16* Wk = W_hi + (size_t)key * W_ks;
  bf16x8 wf[6][4];
#pragma unroll
  for (int j = 0; j < 6; j++)
#pragma unroll
    for (int kk = 0; kk < 4; kk++)
      wf[j][kk] = *(const bf16x8*)(Wk + (size_t)(cb + j * 16 + mq) * D_ + kk * 32 + q * 8);

  const u16* Ah = A_hi + (size_t)key * A_ks + (size_t)(row + mq) * D_;
  const u16* Al = A_lo + (size_t)key * A_ks + (size_t)(row + mq) * D_;
  bf16x8 ah[4], al[4];
#pragma unroll
  for (int kk = 0; kk < 4; kk++) {
    ah[kk] = *(const bf16x8*)(Ah + kk * 32 + q * 8);
    al[kk] = *(const bf16x8*)(Al + kk * 32 + q * 8);
  }

  floatx4 acc[6];
#pragma unroll
  for (int j = 0; j < 6; j++) {
    float bv = bias[key * b_ks + cb + j * 16 + mq];
    acc[j] = {bv, bv, bv, bv};
  }
#pragma unroll
  for (int j = 0; j < 6; j++)
#pragma unroll
    for (int kk = 0; kk < 4; kk++) {
      acc[j] = mfma16(ah[kk], wf[j][kk], acc[j]);
      acc[j] = mfma16(al[kk], wf[j][kk], acc[j]);
    }

  float* op = out + (size_t)key * o_ks + (size_t)(row + q * 4) * G_ + cb + mq;
#pragma unroll
  for (int j = 0; j < 6; j++)
#pragma unroll
    for (int i = 0; i < 4; i++) op[(size_t)i * G_ + j * 16] = acc[j][i];
}

// ---------------- Kernel 4: GRU recurrence (partial unroll x4, fused acc chains) ----------------
template <int MODE, int TT>
__global__ __launch_bounds__(256, 1) void k_gru_t(
    int cpk, const float* __restrict__ xg_a, const float* __restrict__ xg_b,
    const u16* __restrict__ whh_all, const float* __restrict__ bhh_all,
    u16* __restrict__ out_hi, u16* __restrict__ out_lo, float* __restrict__ out_f32) {
  int key = blockIdx.x / cpk;
  int chunk = blockIdx.x % cpk;
  int n0 = chunk * 16;
  const u16* whh = whh_all + (size_t)key * (G_ * D_);
  const float* bhh = bhh_all + (size_t)key * G_;

  __shared__ u16 hls[2][2][16 * 128];

  int tid = threadIdx.x;
  int w = tid >> 6, lane = tid & 63, mq = lane & 15, q = lane >> 4;
  int dA = 16 * w + mq;

  bf16x8 bw[6][4];
#pragma unroll
  for (int j = 0; j < 6; j++)
#pragma unroll
    for (int kk = 0; kk < 4; kk++)
      bw[j][kk] = *(const bf16x8*)(whh + (size_t)(16 * w + 64 * j + mq) * D_ + kk * 32 + q * 8);

  floatx4 bias_v[6];
#pragma unroll
  for (int g = 0; g < 3; g++)
#pragma unroll
    for (int ab = 0; ab < 2; ab++) {
      float b = bhh[g * 128 + ab * 64 + dA];
      bias_v[g * 2 + ab] = {b, b, b, b};
    }

  const float* xbase;
  size_t RS, TS;
  if (MODE == 0) {
    if (key < 3) { xbase = xg_a + ((size_t)key * N_ + n0) * G_; RS = G_; TS = 0; }
    else { xbase = xg_b + ((size_t)(key - 3) * NM_ + (size_t)n0 * M_) * G_; RS = (size_t)M_ * G_; TS = G_; }
  } else {
    xbase = xg_a + (size_t)key * N_ * G_; RS = (size_t)16 * G_; TS = G_;
  }
  const float* rowp[4];
#pragma unroll
  for (int i = 0; i < 4; i++) rowp[i] = xbase + (size_t)(q * 4 + i) * RS + dA;

  float xs[4][24];
#pragma unroll
  for (int s = 0; s < 3; s++) {
    int ts = s < TT ? s : TT - 1;
#pragma unroll
    for (int i = 0; i < 4; i++)
#pragma unroll
      for (int g = 0; g < 3; g++)
#pragma unroll
        for (int ab = 0; ab < 2; ab++)
          xs[s][i * 6 + g * 2 + ab] = rowp[i][(size_t)ts * TS + g * 128 + ab * 64];
  }

  float h_old[8];
#pragma unroll
  for (int k = 0; k < 8; k++) h_old[k] = 0.f;

#define GRU_STEP(P)                                                                        \
  {                                                                                        \
    int t = tb + (P);                                                                      \
    {                                                                                      \
      int tpf = t + 3 < TT ? t + 3 : TT - 1;                                               \
      size_t to = (size_t)tpf * TS;                                                        \
      _Pragma("unroll") for (int i = 0; i < 4; i++)                                        \
          _Pragma("unroll") for (int g = 0; g < 3; g++)                                    \
          _Pragma("unroll") for (int ab = 0; ab < 2; ab++)                                 \
              xs[((P) + 3) & 3][i * 6 + g * 2 + ab] = rowp[i][to + g * 128 + ab * 64];     \
    }                                                                                      \
    floatx4 acc[6];                                                                        \
    if (t > 0) {                                                                           \
      const u16* hp0 = &hls[(t - 1) & 1][0][0];                                            \
      const u16* hp1 = &hls[(t - 1) & 1][1][0];                                            \
      bf16x8 ah[4], al[4];                                                                 \
      _Pragma("unroll") for (int kk = 0; kk < 4; kk++) {                                   \
        int off = mq * 128 + (((kk * 4 + q) ^ mq) * 8);                                    \
        ah[kk] = *(const bf16x8*)(hp0 + off);                                              \
        al[kk] = *(const bf16x8*)(hp1 + off);                                              \
      }                                                                                    \
      _Pragma("unroll") for (int j = 0; j < 6; j++) {                                      \
        floatx4 a = mfma16(ah[0], bw[j][0], bias_v[j]);                                    \
        a = mfma16(al[0], bw[j][0], a);                                                    \
        a = mfma16(ah[1], bw[j][1], a);                                                    \
        a = mfma16(al[1], bw[j][1], a);                                                    \
        a = mfma16(ah[2], bw[j][2], a);                                                    \
        a = mfma16(al[2], bw[j][2], a);                                                    \
        a = mfma16(ah[3], bw[j][3], a);                                                    \
        acc[j] = mfma16(al[3], bw[j][3], a);                                               \
      }                                                                                    \
    } else {                                                                               \
      _Pragma("unroll") for (int j = 0; j < 6; j++) acc[j] = bias_v[j];                    \
    }                                                                                      \
    u16* wrh = &hls[t & 1][0][0];                                                          \
    u16* wrl = &hls[t & 1][1][0];                                                          \
    _Pragma("unroll") for (int i = 0; i < 4; i++) {                                        \
      int row = q * 4 + i;                                                                 \
      _Pragma("unroll") for (int ab = 0; ab < 2; ab++) {                                   \
        float ghr = acc[0 + ab][i];                                                        \
        float ghz = acc[2 + ab][i];                                                        \
        float ghn = acc[4 + ab][i];                                                        \
        float xr = xs[P][i * 6 + 0 + ab];                                                  \
        float xz = xs[P][i * 6 + 2 + ab];                                                  \
        float xnn = xs[P][i * 6 + 4 + ab];                                                 \
        float r = sigm_(xr + ghr);                                                         \
        float z = sigm_(xz + ghz);                                                         \
        float nn = tanh_(xnn + r * ghn);                                                   \
        float h2 = (1.0f - z) * nn + z * h_old[i * 2 + ab];                                \
        h_old[i * 2 + ab] = h2;                                                            \
        u32 ub = __builtin_bit_cast(u32, h2);                                              \
        u16 hb = (u16)(ub >> 16);                                                          \
        float rem = h2 - __builtin_bit_cast(float, ub & 0xFFFF0000u);                      \
        u16 lb = f2bf(rem);                                                                \
        int d = dA + ab * 64;                                                              \
        if (t == TT - 1) {                                                                 \
          if (MODE == 0) {                                                                 \
            size_t o = ((size_t)key * N_ + n0 + row) * D_ + d;                             \
            out_hi[o] = hb;                                                                \
            out_lo[o] = lb;                                                                \
          } else {                                                                         \
            out_f32[((size_t)key * 16 + row) * D_ + d] = h2;                               \
          }                                                                                \
        } else {                                                                           \
          int idx = row * 128 + (((d >> 3) ^ row) * 8) + (d & 7);                          \
          wrh[idx] = hb;                                                                   \
          wrl[idx] = lb;                                                                   \
        }                                                                                  \
      }                                                                                    \
    }                                                                                      \
    if (t + 1 < TT) lds_barrier();                                                         \
  }

#pragma unroll 1
  for (int tb = 0; tb < TT; tb += 4) {
    GRU_STEP(0)
    GRU_STEP(1)
    GRU_STEP(2)
    GRU_STEP(3)
  }
#undef GRU_STEP
}

// ---------------- Kernel 5: ReLU + FC (parallel GEMV) ----------------
__global__ __launch_bounds__(256) void k_fc(
    const float* __restrict__ vis_h, const float* __restrict__ fc_w,
    const float* __restrict__ fc_b, float* __restrict__ out) {
  int b = blockIdx.x;
  int cg = blockIdx.y;
  int tid = threadIdx.x;
  int j = tid & 15, s = tid >> 4;
  int c = cg * 16 + j;
  bool cv = c < OUT_;

  __shared__ float hbuf[7 * D_];
  __shared__ float red[16][16];
  for (int i = tid; i < 7 * D_; i += 256) {
    float v = vis_h[((size_t)(i >> 7) * 16 + b) * D_ + (i & 127)];
    hbuf[i] = v > 0.f ? v : 0.f;
  }
  __syncthreads();

  float acc = 0.f;
  if (cv) {
    const float* wp = fc_w + (size_t)(s * 56) * OUT_ + c;
#pragma unroll 8
    for (int k = 0; k < 56; k++) acc += hbuf[s * 56 + k] * wp[(size_t)k * OUT_];
  }
  red[s][j] = acc;
  __syncthreads();
  if (s == 0 && cv) {
    float t = 0.f;
#pragma unroll
    for (int m = 0; m < 16; m++) t += red[m][j];
    out[(size_t)b * OUT_ + c] = t + fc_b[c];
  }
}

extern "C" void kernel_launch(void* const* d_in, const int* in_sizes, int n_in,
                              void* d_out, int out_size, void* d_ws, size_t ws_size,
                              hipStream_t stream) {
  (void)in_sizes; (void)n_in; (void)out_size; (void)ws_size;
  const int* tok_cond = (const int*)d_in[0];
  const int* tok_proc = (const int*)d_in[1];
  const int* tok_drug = (const int*)d_in[2];
  const int* tok_lab_item = (const int*)d_in[3];
  const int* tok_lab_value = (const int*)d_in[4];
  const int* tok_inj_item = (const int*)d_in[5];
  const int* tok_inj_value = (const int*)d_in[6];
  const float* weight = (const float*)d_in[7];
  const float* age = (const float*)d_in[8];
  const float* emb_cond = (const float*)d_in[9];
  const float* emb_proc = (const float*)d_in[10];
  const float* emb_drug = (const float*)d_in[11];
  const float* emb_lab_item = (const float*)d_in[12];
  const float* emb_lab_value = (const float*)d_in[13];
  const float* emb_inj_item = (const float*)d_in[14];
  const float* emb_inj_value = (const float*)d_in[15];
  const float* mgru_wih = (const float*)d_in[16];
  const float* mgru_whh = (const float*)d_in[17];
  const float* mgru_bih = (const float*)d_in[18];
  const float* mgru_bhh = (const float*)d_in[19];
  const float* vgru_wih = (const float*)d_in[20];
  const float* vgru_whh = (const float*)d_in[21];
  const float* vgru_bih = (const float*)d_in[22];
  const float* vgru_bhh = (const float*)d_in[23];
  const float* info_w = (const float*)d_in[24];
  const float* info_b = (const float*)d_in[25];
  const float* fc_w = (const float*)d_in[26];
  const float* fc_b = (const float*)d_in[27];

  char* p = (char*)d_ws;
  auto take = [&](size_t bytes) { char* r = p; p += (bytes + 255) & ~(size_t)255; return r; };
  u16* mon_x_hi = (u16*)take((size_t)2 * NM_ * D_ * 2);
  u16* mon_x_lo = (u16*)take((size_t)2 * NM_ * D_ * 2);
  u16* ce_hi = (u16*)take((size_t)3 * N_ * D_ * 2);
  u16* ce_lo = (u16*)take((size_t)3 * N_ * D_ * 2);
  u16* vis_x_hi = (u16*)take((size_t)7 * N_ * D_ * 2);
  u16* vis_x_lo = (u16*)take((size_t)7 * N_ * D_ * 2);
  float* xg_mon = (float*)take((size_t)2 * NM_ * G_ * 4);
  float* xg_c = (float*)take((size_t)3 * N_ * G_ * 4);
  float* xg_v = (float*)take((size_t)7 * N_ * G_ * 4);
  float* vis_h = (float*)take((size_t)7 * 16 * D_ * 4);
  u16* wih_hi = (u16*)take((size_t)12 * G_ * D_ * 2);
  u16* wih_lo = (u16*)take((size_t)12 * G_ * D_ * 2);
  u16* whh_hi = (u16*)take((size_t)12 * G_ * D_ * 2);
  u16* whh_lo = (u16*)take((size_t)12 * G_ * D_ * 2);

  k_conv_w<<<(24 * G_ * D_) / 256, 256, 0, stream>>>(mgru_wih, vgru_wih, mgru_whh, vgru_whh,
                                                     wih_hi, wih_lo, whh_hi, whh_lo);
  k_visit_embed<<<N_, D_, 0, stream>>>(tok_cond, tok_proc, tok_drug, emb_cond, emb_proc, emb_drug,
                                       weight, age, info_w, info_b, ce_hi, ce_lo, vis_x_hi, vis_x_lo);
  k_pair_embed<<<NM_, D_, 0, stream>>>(tok_lab_item, tok_lab_value, tok_inj_item, tok_inj_value,
                                       emb_lab_item, emb_lab_value, emb_inj_item, emb_inj_value,
                                       mon_x_hi, mon_x_lo);
  // xg for lab/inj monitor keys (3,4): rows = 8192 each
  k_gemm_xg<<<dim3(NM_ / 64, 4, 2), 256, 0, stream>>>(
      mon_x_hi, mon_x_lo, wih_hi + (size_t)3 * G_ * D_,
      mgru_bih + 3 * G_, xg_mon, NM_ * D_, G_ * D_, G_, NM_ * G_);
  // xg for time-constant monitor keys (0..2): rows = 256 each
  k_gemm_xg<<<dim3(N_ / 64, 4, 3), 256, 0, stream>>>(
      ce_hi, ce_lo, wih_hi, mgru_bih, xg_c, N_ * D_, G_ * D_, G_, N_ * G_);
  k_gru_t<0, 32><<<80, 256, 0, stream>>>(16, xg_c, xg_mon, whh_hi, mgru_bhh,
                                         vis_x_hi, vis_x_lo, nullptr);
  // xg for visit keys (0..6): rows = 256 each
  k_gemm_xg<<<dim3(N_ / 64, 4, 7), 256, 0, stream>>>(
      vis_x_hi, vis_x_lo, wih_hi + (size_t)5 * G_ * D_,
      vgru_bih, xg_v, N_ * D_, G_ * D_, G_, N_ * G_);
  k_gru_t<1, 16><<<7, 256, 0, stream>>>(1, xg_v, nullptr, whh_hi + (size_t)5 * G_ * D_, vgru_bhh,
                                        nullptr, nullptr, vis_h);
  k_fc<<<dim3(B_, 13), 256, 0, stream>>>(vis_h, fc_w, fc_b, (float*)d_out);
}